// Round 8
// baseline (1602.471 us; speedup 1.0000x reference)
//
#include <hip/hip_runtime.h>
#include <cstdint>

#define N_NODES 50000
#define N_EDGES 800000
#define HDIM    128
#define TIE_CAP 44000
#define NITER   2
#define SCAN_B  256

typedef __attribute__((ext_vector_type(8))) short bf16x8;
typedef __attribute__((ext_vector_type(4))) float f32x4;

struct Params {
    const float *h, *e, *attr;
    const float *W_er1, *b_er1, *W_er2, *b_er2;
    const float *W_ih, *W_hh, *b_ih, *b_hh;
    const float *W_nn, *b_nn, *W_g1, *b_g1, *W_g2, *b_g2;
    const int* ei; const void* tie_raw;
    float *out_h, *out_e;
    float *cpl_cnt, *w_den, *deg_inv, *sumw, *w_arr, *m_edge, *csr_w;
    int *hist, *counters, *tie_list, *tie_row, *tie_col;
    int *excl, *bsum, *row_ptr, *cursor, *csr_row;
    short *BTer1, *BTer2, *BTnn, *BTg1, *BTcomb, *BTihn, *BThhn;
    uint16_t *h_bf, *agg;
};

__device__ __forceinline__ uint32_t f2bf(float f) {
    uint32_t u = __builtin_bit_cast(uint32_t, f);
    return (u + 0x7fffu + ((u >> 16) & 1u)) >> 16;   // RNE
}
__device__ __forceinline__ float bf2f(uint32_t b) {
    return __builtin_bit_cast(float, b << 16);
}
__device__ __forceinline__ uint32_t comb2(uint32_t me, uint32_t mn, float g) {
    float a0 = bf2f(me & 0xffffu) + g * bf2f(mn & 0xffffu);
    float a1 = bf2f(me >> 16)     + g * bf2f(mn >> 16);
    return f2bf(a0) | (f2bf(a1) << 16);
}

// ---- 64-row LDS A-tiles: [64 rows][128 bf16] = 256B rows, byte ^= (row&7)<<4

__device__ __forceinline__ void stage_a64(const float* base, const int* gidx,
                                          int m0, int Mlim, char* tile, int tid)
{
    const int c = tid & 15;
    #pragma unroll
    for (int p = 0; p < 4; ++p) {
        int row = p * 16 + (tid >> 4);
        int ar = m0 + row; if (ar >= Mlim) ar = Mlim - 1;
        long g = gidx ? gidx[ar] : ar;
        const float* s = base + g * HDIM + c * 4;
        float4 v0 = *(const float4*)s;
        float4 v1 = *(const float4*)(s + 64);
        uint2 w0 = make_uint2(f2bf(v0.x) | (f2bf(v0.y) << 16),
                              f2bf(v0.z) | (f2bf(v0.w) << 16));
        uint2 w1 = make_uint2(f2bf(v1.x) | (f2bf(v1.y) << 16),
                              f2bf(v1.z) | (f2bf(v1.w) << 16));
        int sw = (row & 7) << 4;
        *(uint2*)(tile + row * 256 + ((c * 8) ^ sw)) = w0;
        *(uint2*)(tile + row * 256 + ((c * 8 + 128) ^ sw)) = w1;
    }
}

__device__ __forceinline__ void stage_abf64(const uint16_t* base, const int* gidx,
                                            int m0, int Mlim, char* tile, int tid)
{
    const int c = tid & 15;
    #pragma unroll
    for (int p = 0; p < 4; ++p) {
        int row = p * 16 + (tid >> 4);
        int ar = m0 + row; if (ar >= Mlim) ar = Mlim - 1;
        long g = gidx ? gidx[ar] : ar;
        uint4 v = *(const uint4*)(base + g * HDIM + c * 8);
        *(uint4*)(tile + row * 256 + ((c * 16) ^ ((row & 7) << 4))) = v;
    }
}

// A from swizzled LDS tile; B DIRECT from global (L2-resident weights, [N][ldk]
// bf16). Wave covers B rows n0 + wc*16 + (lane&15); per K=32 step each lane
// reads 16B; across ks the wave covers 16 rows x 256B contiguous (coalesced).
__device__ __forceinline__ void mfma64g(const char* At, const short* BT, int ldk,
                                        int n0, int k0, int wc, int lane, f32x4* acc)
{
    const short* bp = BT + (size_t)(n0 + wc * 16 + (lane & 15)) * ldk
                       + k0 + (lane >> 4) * 8;
    #pragma unroll
    for (int ks = 0; ks < 4; ++ks) {
        bf16x8 bF = *(const bf16x8*)(bp + ks * 32);
        int kb = ks * 64 + (lane >> 4) * 16;
        #pragma unroll
        for (int mi = 0; mi < 4; ++mi) {
            int row = mi * 16 + (lane & 15);
            bf16x8 aF = *(const bf16x8*)(At + row * 256 + (kb ^ ((row & 7) << 4)));
            acc[mi] = __builtin_amdgcn_mfma_f32_16x16x32_bf16(aF, bF, acc[mi], 0, 0, 0);
        }
    }
}

// ---------------- k_zero: counters + per-node accumulators + fmt detect -----
__global__ __launch_bounds__(256)
void k_zero(Params P)
{
    int i = blockIdx.x * 256 + threadIdx.x;
    if (i < N_NODES) { P.cpl_cnt[i] = 0.f; P.w_den[i] = 0.f; P.hist[i] = 0; }
    if (blockIdx.x == 0 && threadIdx.x < 64) {
        const uint8_t* tr = (const uint8_t*)P.tie_raw;
        int c = 0;
        for (int k = threadIdx.x; k < 4096; k += 64)
            if ((k & 3) && tr[k]) c = 1;
        unsigned long long m = __ballot(c != 0);
        if (threadIdx.x == 0) {
            P.counters[0] = (m != 0ull) ? 1 : 0;
            P.counters[1] = 0; P.counters[2] = 0;
        }
    }
}

// ---------------- k_prep: copies + weight prep + tie classification ---------
__global__ __launch_bounds__(256)
void k_prep(Params P)
{
    const int gtid = blockIdx.x * 256 + threadIdx.x;
    const int gstr = gridDim.x * 256;
    // h -> out_h + h_bf
    for (int i = gtid; i < N_NODES * HDIM / 4; i += gstr) {
        float4 v = ((const float4*)P.h)[i];
        ((float4*)P.out_h)[i] = v;
        *(uint2*)(P.h_bf + (size_t)i * 4) =
            make_uint2(f2bf(v.x) | (f2bf(v.y) << 16), f2bf(v.z) | (f2bf(v.w) << 16));
    }
    // e -> out_e (bulk of this kernel; HBM-bound)
    for (int i = gtid; i < N_EDGES * HDIM / 4; i += gstr)
        ((float4*)P.out_e)[i] = ((const float4*)P.e)[i];
    // m_edge zero for iteration 1
    for (int i = gtid; i < N_NODES * HDIM / 4; i += gstr)
        ((float4*)P.m_edge)[i] = make_float4(0.f, 0.f, 0.f, 0.f);
    // weights -> bf16 [N][K]
    for (int i = gtid; i < 384 * 256; i += gstr) { int n = i / 384, k = i % 384; P.BTer1[i] = (short)f2bf(P.W_er1[(size_t)k * 256 + n]); }
    for (int i = gtid; i < 128 * 256; i += gstr) { int n = i / 256, k = i % 256; P.BTer2[i] = (short)f2bf(P.W_er2[(size_t)k * 128 + n]); }
    for (int i = gtid; i < 128 * 128; i += gstr) { int n = i / 128, k = i % 128; P.BTnn[i]  = (short)f2bf(P.W_nn [(size_t)k * 128 + n]); }
    for (int i = gtid; i < 128 * 384; i += gstr) { int n = i / 384, k = i % 384; P.BTg1[i]  = (short)f2bf(P.W_g1 [(size_t)k * 128 + n]); }
    for (int i = gtid; i < 256 * 256; i += gstr) { int n = i >> 8, k = i & 255; float v = (k < 128) ? P.W_ih[n * 128 + k] : P.W_hh[n * 128 + (k - 128)]; P.BTcomb[i] = (short)f2bf(v); }
    for (int i = gtid; i < 128 * 128; i += gstr) { P.BTihn[i] = (short)f2bf(P.W_ih[256 * 128 + i]); P.BThhn[i] = (short)f2bf(P.W_hh[256 * 128 + i]); }
    // tie classification + wave-aggregated compaction (fmt from k_zero)
    int fmt = P.counters[0];
    for (int e = gtid; e < N_EDGES; e += gstr) {
        bool t = fmt ? (((const uint8_t*)P.tie_raw)[e] != 0)
                     : (((const int*)P.tie_raw)[e] != 0);
        int r = 0, c = 0;
        if (t) {
            r = P.ei[e]; c = P.ei[N_EDGES + e];
            atomicAdd(&P.cpl_cnt[r], 1.f);
            atomicAdd(&P.cpl_cnt[c], 1.f);
        }
        unsigned long long m = __ballot(t);
        if (m) {
            int lane = threadIdx.x & 63;
            int first = __ffsll((unsigned long long)m) - 1;
            int base = 0;
            if (lane == first) base = atomicAdd(&P.counters[1], __popcll(m));
            base = __shfl(base, first);
            if (t) {
                int idx = base + __popcll(m & ((1ull << lane) - 1ull));
                if (idx < TIE_CAP) {
                    P.tie_list[idx] = e; P.tie_row[idx] = r; P.tie_col[idx] = c;
                }
            }
        }
    }
}

__global__ __launch_bounds__(256)
void k_w(Params P)
{
    int e = blockIdx.x * 256 + threadIdx.x;
    if (e >= N_EDGES) return;
    int fmt = P.counters[0];
    bool t = fmt ? (((const uint8_t*)P.tie_raw)[e] != 0)
                 : (((const int*)P.tie_raw)[e] != 0);
    float w = 0.f;
    if (!t) {
        int c = P.ei[N_EDGES + e];
        if (P.cpl_cnt[c] > 0.f) {
            float X = fabsf(P.attr[(size_t)e * 10 + 1]);
            w = 1.f / sqrtf(X * X + 1e-6f);
            atomicAdd(&P.w_den[c], w);
            atomicAdd(&P.hist[c], 1);
        }
    }
    P.w_arr[e] = w;
}

// ---------------- CSR build ----------------
__global__ __launch_bounds__(SCAN_B)
void k_scan1(Params P)
{
    __shared__ int s[SCAN_B];
    int t = threadIdx.x;
    int i = blockIdx.x * SCAN_B + t;
    int v = (i < N_NODES) ? P.hist[i] : 0;
    s[t] = v;
    __syncthreads();
    for (int o = 1; o < SCAN_B; o <<= 1) {
        int u = (t >= o) ? s[t - o] : 0;
        __syncthreads();
        s[t] += u;
        __syncthreads();
    }
    if (i < N_NODES) P.excl[i] = s[t] - v;
    if (t == SCAN_B - 1) P.bsum[blockIdx.x] = s[t];
}

__global__ void k_scan2(Params P)
{
    const int NB = (N_NODES + SCAN_B - 1) / SCAN_B;
    if (threadIdx.x == 0) {
        int run = 0;
        for (int b = 0; b < NB; ++b) { int x = P.bsum[b]; P.bsum[b] = run; run += x; }
        P.counters[2] = run;
    }
}

__global__ __launch_bounds__(256)
void k_scan3(Params P)   // + deg_inv / sumw fused
{
    int i = blockIdx.x * 256 + threadIdx.x;
    if (i < N_NODES) {
        int v = P.excl[i] + P.bsum[i >> 8];
        P.row_ptr[i] = v;
        P.cursor[i] = v;
        P.deg_inv[i] = 1.f / fmaxf(P.cpl_cnt[i], 1.f);
        float wd = P.w_den[i];
        P.sumw[i] = wd / (wd + 1e-6f);
    }
    if (i == N_NODES) P.row_ptr[N_NODES] = P.counters[2];
}

__global__ __launch_bounds__(256)
void k_fill(Params P)   // + w-normalization fused
{
    int e = blockIdx.x * 256 + threadIdx.x;
    if (e >= N_EDGES) return;
    float w = P.w_arr[e];
    if (w == 0.f) return;
    int c = P.ei[N_EDGES + e];
    int pos = atomicAdd(&P.cursor[c], 1);
    P.csr_row[pos] = P.ei[e];
    P.csr_w[pos] = w / (P.w_den[c] + 1e-6f);
}

// ---------------- tie tiles + gather, co-scheduled in one grid --------------
#define GT_BLOCKS (TIE_CAP / 64)            // 688
#define GG_BLOCKS ((N_NODES + 3) / 4)       // 12500

__global__ __launch_bounds__(256, 3)
void k_tie_gather(Params P)
{
    const int tid = threadIdx.x, lane = tid & 63, wc = tid >> 6;

    if ((int)blockIdx.x >= GT_BLOCKS) {
        // ---- gather: agg[n] = sum w_norm * h_bf[row] ----
        int n = ((int)blockIdx.x - GT_BLOCKS) * 4 + wc;
        if (n >= N_NODES) return;
        int s = P.row_ptr[n], t = P.row_ptr[n + 1];
        float a0 = 0.f, a1 = 0.f;
        for (int j = s; j < t; ++j) {
            int r = P.csr_row[j];
            float w = P.csr_w[j];
            uint32_t v = *(const uint32_t*)(P.h_bf + (size_t)r * HDIM + lane * 2);
            a0 += w * bf2f(v & 0xffffu);
            a1 += w * bf2f(v >> 16);
        }
        *(uint32_t*)(P.agg + (size_t)n * HDIM + lane * 2) = f2bf(a0) | (f2bf(a1) << 16);
        return;
    }

    // ---- tie tile: L1 -> relu -> L2 -> e upd + m_edge scatter ----
    int cnt = P.counters[1]; if (cnt > TIE_CAP) cnt = TIE_CAP;
    const int m0 = blockIdx.x * 64;
    if (cnt == 0 || m0 >= cnt) return;

    __shared__ __align__(16) char At[16 * 1024];
    __shared__ __align__(16) char Ct[16 * 1024];

    const int l = lane & 15, rg = (lane >> 4) << 2;

    f32x4 acc1[4][4] = {};   // [q of N=256][mi]
    #pragma unroll 1
    for (int c3 = 0; c3 < 3; ++c3) {
        if (c3 == 0) stage_a64(P.out_e, P.tie_list, m0, cnt, At, tid);
        else         stage_abf64(P.h_bf, (c3 == 1) ? P.tie_row : P.tie_col, m0, cnt, At, tid);
        __syncthreads();
        #pragma unroll 1
        for (int q = 0; q < 4; ++q)
            mfma64g(At, P.BTer1, 384, q * 64, c3 * 128, wc, lane, acc1[q]);
        __syncthreads();
    }

    // C1 = relu(acc1 + b_er1) -> bf16 into At (k 0-127) / Ct (k 128-255)
    #pragma unroll
    for (int q = 0; q < 4; ++q) {
        int col = q * 64 + wc * 16 + l;
        float bv = P.b_er1[col];
        char* T = (q < 2) ? At : Ct;
        int cl = col & 127;
        #pragma unroll
        for (int mi = 0; mi < 4; ++mi)
            #pragma unroll
            for (int j = 0; j < 4; ++j) {
                int row = mi * 16 + rg + j;
                float v = fmaxf(acc1[q][mi][j] + bv, 0.f);
                *(uint16_t*)(T + row * 256 + ((cl * 2) ^ ((row & 7) << 4))) =
                    (uint16_t)f2bf(v);
            }
    }
    __syncthreads();

    // L2 (K=256), no barriers
    f32x4 acc2[2][4] = {};
    #pragma unroll 1
    for (int c2 = 0; c2 < 2; ++c2)
        #pragma unroll 1
        for (int hh = 0; hh < 2; ++hh)
            mfma64g(c2 ? Ct : At, P.BTer2, 256, hh * 64, c2 * 128, wc, lane, acc2[hh]);

    // epilogue: e_work += eref; scatter v*deg_inv into m_edge
    #pragma unroll
    for (int mi = 0; mi < 4; ++mi)
        #pragma unroll
        for (int j = 0; j < 4; ++j) {
            int i = m0 + mi * 16 + rg + j;
            if (i < cnt) {
                int e = P.tie_list[i], r = P.tie_row[i], cc = P.tie_col[i];
                float dr = P.deg_inv[r], dc = P.deg_inv[cc];
                #pragma unroll
                for (int hh = 0; hh < 2; ++hh) {
                    int col = hh * 64 + wc * 16 + l;
                    float er = acc2[hh][mi][j] + P.b_er2[col];
                    size_t eb = (size_t)e * HDIM + col;
                    float v = P.out_e[eb] + er;
                    P.out_e[eb] = v;
                    atomicAdd(&P.m_edge[(size_t)r * HDIM + col], v * dr);
                    atomicAdd(&P.m_edge[(size_t)cc * HDIM + col], v * dc);
                }
            }
        }
}

// ---------------- mega node kernel: 6 syncs total, GRU barrier-free ---------
__global__ __launch_bounds__(256, 2)
void k_mega(Params P)
{
    const int m0 = blockIdx.x * 64;
    __shared__ __align__(16) char Tme[16 * 1024];
    __shared__ __align__(16) char Tmn[16 * 1024];   // agg -> m_node -> M
    __shared__ __align__(16) char Th [16 * 1024];
    __shared__ float g_red[4][64];
    __shared__ float g_fin[64];

    const int tid = threadIdx.x, lane = tid & 63, wc = tid >> 6;
    const int l = lane & 15, rg = (lane >> 4) << 2;

    stage_a64(P.m_edge, nullptr, m0, N_NODES, Tme, tid);
    stage_abf64(P.agg,  nullptr, m0, N_NODES, Tmn, tid);
    stage_abf64(P.h_bf, nullptr, m0, N_NODES, Th,  tid);
    __syncthreads();                                   // sync 1

    // self-zero own m_edge rows for the next iteration (Tme already staged)
    {
        int lim = (N_NODES - m0 < 64 ? N_NODES - m0 : 64) * HDIM / 4;
        float4* mp = (float4*)(P.m_edge + (size_t)m0 * HDIM);
        for (int i2 = tid; i2 < lim; i2 += 256)
            mp[i2] = make_float4(0.f, 0.f, 0.f, 0.f);
    }

    // phase0: m_node = agg @ W_nn + sumw*b_nn
    f32x4 accM[2][4] = {};
    #pragma unroll 1
    for (int hh = 0; hh < 2; ++hh)
        mfma64g(Tmn, P.BTnn, 128, hh * 64, 0, wc, lane, accM[hh]);
    __syncthreads();                                   // sync 2 (Tmn reads done)
    #pragma unroll
    for (int hh = 0; hh < 2; ++hh) {
        int col = hh * 64 + wc * 16 + l;
        float bv = P.b_nn[col];
        #pragma unroll
        for (int mi = 0; mi < 4; ++mi)
            #pragma unroll
            for (int j = 0; j < 4; ++j) {
                int row = mi * 16 + rg + j;
                int node = m0 + row; if (node >= N_NODES) node = N_NODES - 1;
                float v = accM[hh][mi][j] + P.sumw[node] * bv;
                *(uint16_t*)(Tmn + row * 256 + ((col * 2) ^ ((row & 7) << 4))) =
                    (uint16_t)f2bf(v);
            }
    }
    __syncthreads();                                   // sync 3

    // gate: [me|mn|h](K=384) @ W_g1 — no barriers
    f32x4 accG[2][4] = {};
    #pragma unroll 1
    for (int c3 = 0; c3 < 3; ++c3) {
        const char* Ax = (c3 == 0) ? Tme : (c3 == 1) ? Tmn : Th;
        #pragma unroll 1
        for (int hh = 0; hh < 2; ++hh)
            mfma64g(Ax, P.BTg1, 384, hh * 64, c3 * 128, wc, lane, accG[hh]);
    }
    #pragma unroll
    for (int mi = 0; mi < 4; ++mi)
        #pragma unroll
        for (int j = 0; j < 4; ++j) {
            float p = 0.f;
            #pragma unroll
            for (int hh = 0; hh < 2; ++hh) {
                int col = hh * 64 + wc * 16 + l;
                p += fmaxf(accG[hh][mi][j] + P.b_g1[col], 0.f) * P.W_g2[col];
            }
            #pragma unroll
            for (int o = 8; o; o >>= 1) p += __shfl_xor(p, o);
            if (l == 0) g_red[wc][mi * 16 + rg + j] = p;
        }
    __syncthreads();                                   // sync 4
    if (tid < 64) {
        float t = g_red[0][tid] + g_red[1][tid] + g_red[2][tid] + g_red[3][tid]
                + P.b_g2[0];
        g_fin[tid] = 1.f / (1.f + __expf(-t));
    }
    __syncthreads();                                   // sync 5

    // M = me + g*mn (bf16, in place of Tmn; per-thread disjoint positions)
    {
        const int c = tid & 15;
        #pragma unroll
        for (int p2 = 0; p2 < 4; ++p2) {
            int row = p2 * 16 + (tid >> 4);
            float g = g_fin[row];
            int sw = (row & 7) << 4;
            #pragma unroll
            for (int hh = 0; hh < 2; ++hh) {
                int off = (c * 8 + hh * 128) ^ sw;
                uint2 me2 = *(uint2*)(Tme + row * 256 + off);
                uint2 mn2 = *(uint2*)(Tmn + row * 256 + off);
                *(uint2*)(Tmn + row * 256 + off) =
                    make_uint2(comb2(me2.x, mn2.x, g), comb2(me2.y, mn2.y, g));
            }
        }
    }
    __syncthreads();                                   // sync 6

    // GRU: 12 GEMM phases, ZERO barriers (A from LDS, B from L2)
    f32x4 aR[2][4] = {}, aZ[2][4] = {}, aGI[2][4] = {}, aGH[2][4] = {};
    #pragma unroll 1
    for (int ac = 0; ac < 2; ++ac) {
        const char* Ax = ac ? Th : Tmn;
        #pragma unroll 1
        for (int hh = 0; hh < 2; ++hh)
            mfma64g(Ax, P.BTcomb, 256, hh * 64, ac * 128, wc, lane, aR[hh]);
        #pragma unroll 1
        for (int hh = 0; hh < 2; ++hh)
            mfma64g(Ax, P.BTcomb, 256, 128 + hh * 64, ac * 128, wc, lane, aZ[hh]);
    }
    #pragma unroll 1
    for (int hh = 0; hh < 2; ++hh)
        mfma64g(Tmn, P.BTihn, 128, hh * 64, 0, wc, lane, aGI[hh]);
    #pragma unroll 1
    for (int hh = 0; hh < 2; ++hh)
        mfma64g(Th, P.BThhn, 128, hh * 64, 0, wc, lane, aGH[hh]);

    // GRU epilogue (masked); maintains h_bf shadow
    #pragma unroll
    for (int hh = 0; hh < 2; ++hh) {
        int col = hh * 64 + wc * 16 + l;
        float br  = P.b_ih[col] + P.b_hh[col];
        float bz  = P.b_ih[128 + col] + P.b_hh[128 + col];
        float bin = P.b_ih[256 + col], bhn = P.b_hh[256 + col];
        #pragma unroll
        for (int mi = 0; mi < 4; ++mi)
            #pragma unroll
            for (int j = 0; j < 4; ++j) {
                int node = m0 + mi * 16 + rg + j;
                if (node < N_NODES && P.cpl_cnt[node] > 0.f) {
                    float r = 1.f / (1.f + __expf(-(aR[hh][mi][j] + br)));
                    float z = 1.f / (1.f + __expf(-(aZ[hh][mi][j] + bz)));
                    float nn = tanhf(aGI[hh][mi][j] + bin + r * (aGH[hh][mi][j] + bhn));
                    size_t hb = (size_t)node * HDIM + col;
                    float hv = P.out_h[hb];
                    float hn = (1.f - z) * nn + z * hv;
                    P.out_h[hb] = hn;
                    P.h_bf[hb] = (uint16_t)f2bf(hn);
                }
            }
    }
}

// ---------------- launch ----------------
extern "C" void kernel_launch(void* const* d_in, const int* in_sizes, int n_in,
                              void* d_out, int out_size, void* d_ws, size_t ws_size,
                              hipStream_t stream)
{
    Params P;
    P.h     = (const float*)d_in[0];
    P.e     = (const float*)d_in[1];
    P.attr  = (const float*)d_in[2];
    P.W_er1 = (const float*)d_in[3];
    P.b_er1 = (const float*)d_in[4];
    P.W_er2 = (const float*)d_in[5];
    P.b_er2 = (const float*)d_in[6];
    P.W_ih  = (const float*)d_in[7];
    P.W_hh  = (const float*)d_in[8];
    P.b_ih  = (const float*)d_in[9];
    P.b_hh  = (const float*)d_in[10];
    P.W_nn  = (const float*)d_in[11];
    P.b_nn  = (const float*)d_in[12];
    P.W_g1  = (const float*)d_in[13];
    P.b_g1  = (const float*)d_in[14];
    P.W_g2  = (const float*)d_in[15];
    P.b_g2  = (const float*)d_in[16];
    P.ei    = (const int*)d_in[17];
    P.tie_raw = d_in[18];

    P.out_h = (float*)d_out;
    P.out_e = P.out_h + (size_t)N_NODES * HDIM;

    char* ws = (char*)d_ws;
    size_t off = 0;
    auto alloc = [&](size_t bytes) -> void* {
        void* p = ws + off;
        off = (off + bytes + 255) & ~(size_t)255;
        return p;
    };
    P.cpl_cnt = (float*)alloc((size_t)N_NODES * 4);
    P.w_den   = (float*)alloc((size_t)N_NODES * 4);
    P.hist    = (int*)  alloc((size_t)N_NODES * 4);
    P.counters= (int*)  alloc(256);
    P.deg_inv = (float*)alloc((size_t)N_NODES * 4);
    P.sumw    = (float*)alloc((size_t)N_NODES * 4);
    P.w_arr   = (float*)alloc((size_t)N_EDGES * 4);
    P.tie_list= (int*)alloc((size_t)TIE_CAP * 4);
    P.tie_row = (int*)alloc((size_t)TIE_CAP * 4);
    P.tie_col = (int*)alloc((size_t)TIE_CAP * 4);
    P.BTer1   = (short*)alloc((size_t)256 * 384 * 2);
    P.BTer2   = (short*)alloc((size_t)128 * 256 * 2);
    P.BTnn    = (short*)alloc((size_t)128 * 128 * 2);
    P.BTg1    = (short*)alloc((size_t)128 * 384 * 2);
    P.BTcomb  = (short*)alloc((size_t)256 * 256 * 2);
    P.BTihn   = (short*)alloc((size_t)128 * 128 * 2);
    P.BThhn   = (short*)alloc((size_t)128 * 128 * 2);
    P.h_bf    = (uint16_t*)alloc((size_t)N_NODES * HDIM * 2);
    P.agg     = (uint16_t*)alloc((size_t)N_NODES * HDIM * 2);
    P.m_edge  = (float*)alloc((size_t)N_NODES * HDIM * 4);
    P.excl    = (int*)alloc((size_t)N_NODES * 4);
    P.bsum    = (int*)alloc(256 * 4);
    P.row_ptr = (int*)alloc((size_t)(N_NODES + 1) * 4);
    P.cursor  = (int*)alloc((size_t)N_NODES * 4);
    P.csr_row = (int*)alloc((size_t)N_EDGES * 4);
    P.csr_w   = (float*)alloc((size_t)N_EDGES * 4);
    if (off > ws_size) return;

    const int EB = N_EDGES / 256;                     // 3125
    const int NB = (N_NODES + SCAN_B - 1) / SCAN_B;   // 196
    const int GN = (N_NODES + 63) / 64;               // 782

    k_zero <<<NB, 256, 0, stream>>>(P);
    k_prep <<<2048, 256, 0, stream>>>(P);
    k_w    <<<EB, 256, 0, stream>>>(P);
    k_scan1<<<NB, SCAN_B, 0, stream>>>(P);
    k_scan2<<<1, 64, 0, stream>>>(P);
    k_scan3<<<NB, 256, 0, stream>>>(P);
    k_fill <<<EB, 256, 0, stream>>>(P);

    for (int it = 0; it < NITER; ++it) {
        k_tie_gather<<<GT_BLOCKS + GG_BLOCKS, 256, 0, stream>>>(P);
        k_mega      <<<GN, 256, 0, stream>>>(P);
    }
}

// Round 9
// 913.446 us; speedup vs baseline: 1.7543x; 1.7543x over previous
//
#include <hip/hip_runtime.h>
#include <cstdint>

#define N_NODES 50000
#define N_EDGES 800000
#define HDIM    128
#define TIE_CAP 44000
#define NITER   2
#define SCAN_B  256

typedef __attribute__((ext_vector_type(8))) short bf16x8;
typedef __attribute__((ext_vector_type(4))) float f32x4;

__device__ __forceinline__ uint32_t f2bf(float f) {
    uint32_t u = __builtin_bit_cast(uint32_t, f);
    return (u + 0x7fffu + ((u >> 16) & 1u)) >> 16;   // RNE
}
__device__ __forceinline__ float bf2f(uint32_t b) {
    return __builtin_bit_cast(float, b << 16);
}
__device__ __forceinline__ uint32_t comb2(uint32_t me, uint32_t mn, float g) {
    float a0 = bf2f(me & 0xffffu) + g * bf2f(mn & 0xffffu);
    float a1 = bf2f(me >> 16)     + g * bf2f(mn >> 16);
    return f2bf(a0) | (f2bf(a1) << 16);
}

// ---- LDS tiles: [128 rows][128 bf16] = 256B rows, byte ^= (row&7)<<4 ----

__device__ __forceinline__ void stage_a128(const float* __restrict__ base,
                                           const int* __restrict__ gidx,
                                           int m0, int Mlim, char* tile, int tid)
{
    const int c = tid & 15;
    #pragma unroll
    for (int p = 0; p < 4; ++p) {
        int row = p * 32 + (tid >> 4);
        int ar = m0 + row; if (ar >= Mlim) ar = Mlim - 1;
        long g = gidx ? gidx[ar] : ar;
        const float* s = base + g * HDIM + c * 4;
        float4 v0 = *(const float4*)s;
        float4 v1 = *(const float4*)(s + 64);
        uint2 w0 = make_uint2(f2bf(v0.x) | (f2bf(v0.y) << 16),
                              f2bf(v0.z) | (f2bf(v0.w) << 16));
        uint2 w1 = make_uint2(f2bf(v1.x) | (f2bf(v1.y) << 16),
                              f2bf(v1.z) | (f2bf(v1.w) << 16));
        int sw = (row & 7) << 4;
        *(uint2*)(tile + row * 256 + ((c * 8) ^ sw)) = w0;
        *(uint2*)(tile + row * 256 + ((c * 8 + 128) ^ sw)) = w1;
    }
}

__device__ __forceinline__ void stage_bf128(const uint16_t* __restrict__ base,
                                            const int* __restrict__ gidx,
                                            int m0, int Mlim, char* tile, int tid)
{
    const int c = tid & 15;
    #pragma unroll
    for (int p = 0; p < 4; ++p) {
        int row = p * 32 + (tid >> 4);
        int ar = m0 + row; if (ar >= Mlim) ar = Mlim - 1;
        long g = gidx ? gidx[ar] : ar;
        uint4 v = *(const uint4*)(base + g * HDIM + c * 8);
        *(uint4*)(tile + row * 256 + ((c * 16) ^ ((row & 7) << 4))) = v;
    }
}

__device__ __forceinline__ void stage_b128(const short* __restrict__ BT, int ldk,
                                           int n0, int k0, char* tile, int tid)
{
    const int c = tid & 15;
    #pragma unroll
    for (int p = 0; p < 4; ++p) {
        int n = p * 32 + (tid >> 4);
        uint4 v = *(const uint4*)&BT[(size_t)(n0 + n) * ldk + k0 + c * 8];
        *(uint4*)(tile + n * 256 + ((c * 16) ^ ((n & 7) << 4))) = v;
    }
}

// one K=128 chunk: 8 waves in 2(M)x4(N); wave does 64x32 via 16x16x32 MFMA
__device__ __forceinline__ void mfma128(const char* At, const char* Bt,
                                        int wr, int wc, int lane, f32x4 acc[4][2])
{
    #pragma unroll
    for (int ks = 0; ks < 2; ++ks) {
        int kb = ks * 64 + (lane >> 4) * 16;
        bf16x8 aF[4], bF[2];
        #pragma unroll
        for (int mi = 0; mi < 4; ++mi) {
            int row = wr * 64 + mi * 16 + (lane & 15);
            aF[mi] = *(const bf16x8*)(At + row * 256 + (kb ^ ((row & 7) << 4)));
        }
        #pragma unroll
        for (int ni = 0; ni < 2; ++ni) {
            int n = wc * 32 + ni * 16 + (lane & 15);
            bF[ni] = *(const bf16x8*)(Bt + n * 256 + (kb ^ ((n & 7) << 4)));
        }
        #pragma unroll
        for (int mi = 0; mi < 4; ++mi)
            #pragma unroll
            for (int ni = 0; ni < 2; ++ni)
                acc[mi][ni] = __builtin_amdgcn_mfma_f32_16x16x32_bf16(
                    aF[mi], bF[ni], acc[mi][ni], 0, 0, 0);
    }
    #pragma unroll
    for (int ks = 2; ks < 4; ++ks) {
        int kb = ks * 64 + (lane >> 4) * 16;
        bf16x8 aF[4], bF[2];
        #pragma unroll
        for (int mi = 0; mi < 4; ++mi) {
            int row = wr * 64 + mi * 16 + (lane & 15);
            aF[mi] = *(const bf16x8*)(At + row * 256 + (kb ^ ((row & 7) << 4)));
        }
        #pragma unroll
        for (int ni = 0; ni < 2; ++ni) {
            int n = wc * 32 + ni * 16 + (lane & 15);
            bF[ni] = *(const bf16x8*)(Bt + n * 256 + (kb ^ ((n & 7) << 4)));
        }
        #pragma unroll
        for (int mi = 0; mi < 4; ++mi)
            #pragma unroll
            for (int ni = 0; ni < 2; ++ni)
                acc[mi][ni] = __builtin_amdgcn_mfma_f32_16x16x32_bf16(
                    aF[mi], bF[ni], acc[mi][ni], 0, 0, 0);
    }
}

// ---------------- fused tie-edge kernel (champion R5 code) ------------------
__global__ __launch_bounds__(512)
void k_tie_fused(float* __restrict__ out_e, const uint16_t* __restrict__ h_bf,
                 const int* __restrict__ tie_cnt_p,
                 const int* __restrict__ tie_list, const int* __restrict__ tie_row,
                 const int* __restrict__ tie_col,
                 const short* __restrict__ BTer1, const short* __restrict__ BTer2,
                 const float* __restrict__ b_er1, const float* __restrict__ b_er2,
                 const float* __restrict__ deg_inv, float* __restrict__ m_edge)
{
    int cnt = *tie_cnt_p; if (cnt > TIE_CAP) cnt = TIE_CAP;
    const int m0 = blockIdx.x * 128;
    if (m0 >= cnt) return;

    __shared__ __align__(16) char At[32 * 1024];
    __shared__ __align__(16) char B0[32 * 1024];
    __shared__ __align__(16) char B1[32 * 1024];

    const int tid = threadIdx.x, lane = tid & 63;
    const int wid = tid >> 6, wr = wid >> 2, wc = wid & 3;

    f32x4 acc0[4][2] = {}, acc1[4][2] = {};
    #pragma unroll 1
    for (int c = 0; c < 3; ++c) {
        if (c == 0) stage_a128(out_e, tie_list, m0, cnt, At, tid);
        else        stage_bf128(h_bf, (c == 1) ? tie_row : tie_col, m0, cnt, At, tid);
        stage_b128(BTer1, 384, 0,   c * 128, B0, tid);
        stage_b128(BTer1, 384, 128, c * 128, B1, tid);
        __syncthreads();
        mfma128(At, B0, wr, wc, lane, acc0);
        mfma128(At, B1, wr, wc, lane, acc1);
        __syncthreads();
    }

    // epilogue1: relu(acc+b) -> bf16 C1 tiles (At = cols 0-127, B0 = 128-255)
    #pragma unroll
    for (int half = 0; half < 2; ++half) {
        char* Ct = half ? B0 : At;
        #pragma unroll
        for (int ni = 0; ni < 2; ++ni) {
            int col = wc * 32 + ni * 16 + (lane & 15);
            float bv = b_er1[half * 128 + col];
            #pragma unroll
            for (int mi = 0; mi < 4; ++mi)
                #pragma unroll
                for (int j = 0; j < 4; ++j) {
                    int rl = wr * 64 + mi * 16 + ((lane >> 4) << 2) + j;
                    float v = fmaxf((half ? acc1 : acc0)[mi][ni][j] + bv, 0.f);
                    *(uint16_t*)(Ct + rl * 256 + ((col * 2) ^ ((rl & 7) << 4))) =
                        (uint16_t)f2bf(v);
                }
        }
    }
    stage_b128(BTer2, 256, 0, 0, B1, tid);
    __syncthreads();
    f32x4 acc2[4][2] = {};
    mfma128(At, B1, wr, wc, lane, acc2);
    __syncthreads();
    stage_b128(BTer2, 256, 0, 128, B1, tid);
    __syncthreads();
    mfma128(B0, B1, wr, wc, lane, acc2);

    // epilogue2: e_work += eref; scatter v*deg_inv into m_edge
    int col0 = wc * 32 + (lane & 15);
    float bv0 = b_er2[col0], bv1 = b_er2[col0 + 16];
    #pragma unroll
    for (int mi = 0; mi < 4; ++mi) {
        #pragma unroll
        for (int j = 0; j < 4; ++j) {
            int i = m0 + wr * 64 + mi * 16 + ((lane >> 4) << 2) + j;
            if (i < cnt) {
                int e = tie_list[i], r = tie_row[i], cc = tie_col[i];
                float dr = deg_inv[r], dc = deg_inv[cc];
                #pragma unroll
                for (int ni = 0; ni < 2; ++ni) {
                    int col = col0 + ni * 16;
                    float er = acc2[mi][ni][j] + (ni ? bv1 : bv0);
                    size_t eb = (size_t)e * HDIM + col;
                    float v = out_e[eb] + er;
                    out_e[eb] = v;
                    atomicAdd(&m_edge[(size_t)r * HDIM + col], v * dr);
                    atomicAdd(&m_edge[(size_t)cc * HDIM + col], v * dc);
                }
            }
        }
    }
}

// ---------------- fused node kernel (champion R5 code + self-zero) ----------
__global__ __launch_bounds__(512)
void k_node_mega(float* __restrict__ m_edge, const uint16_t* __restrict__ agg,
                 float* __restrict__ out_h, uint16_t* __restrict__ h_bf,
                 const float* __restrict__ cpl_cnt, const float* __restrict__ sumw,
                 const short* __restrict__ BTnn, const float* __restrict__ b_nn,
                 const short* __restrict__ BTg1, const float* __restrict__ b_g1,
                 const float* __restrict__ Wg2, const float* __restrict__ b_g2,
                 const short* __restrict__ BTcomb,
                 const short* __restrict__ BTihn, const short* __restrict__ BThhn,
                 const float* __restrict__ b_ih, const float* __restrict__ b_hh)
{
    const int m0 = blockIdx.x * 128;
    __shared__ __align__(16) char Tme[32 * 1024];
    __shared__ __align__(16) char Tmn[32 * 1024];   // agg -> m_node -> M
    __shared__ __align__(16) char Th [32 * 1024];
    __shared__ __align__(16) char Bt [32 * 1024];
    __shared__ float g_red[4][128];
    __shared__ float g_fin[128];
    __shared__ float sw_s[128];

    const int tid = threadIdx.x, lane = tid & 63;
    const int wid = tid >> 6, wr = wid >> 2, wc = wid & 3;

    stage_a128(m_edge, nullptr, m0, N_NODES, Tme, tid);
    stage_bf128(agg,   nullptr, m0, N_NODES, Tmn, tid);
    stage_bf128(h_bf,  nullptr, m0, N_NODES, Th,  tid);
    stage_b128(BTnn, 128, 0, 0, Bt, tid);
    if (tid < 128) {
        int n = m0 + tid; if (n >= N_NODES) n = N_NODES - 1;
        sw_s[tid] = sumw[n];
    }
    __syncthreads();

    // self-zero own m_edge rows for the NEXT iteration (Tme already staged;
    // blocks partition node ranges, so no cross-block hazard)
    {
        int lim = (N_NODES - m0 < 128 ? N_NODES - m0 : 128) * HDIM / 4;
        float4* mp = (float4*)(m_edge + (size_t)m0 * HDIM);
        for (int i2 = tid; i2 < lim; i2 += 512)
            mp[i2] = make_float4(0.f, 0.f, 0.f, 0.f);
    }

    // ---- phase 0: m_node = agg @ W_nn + sumw*b_nn  -> bf16 into Tmn ----
    {
        f32x4 accM[4][2] = {};
        mfma128(Tmn, Bt, wr, wc, lane, accM);
        __syncthreads();   // all reads of Tmn done before overwrite
        #pragma unroll
        for (int ni = 0; ni < 2; ++ni) {
            int col = wc * 32 + ni * 16 + (lane & 15);
            float bv = b_nn[col];
            #pragma unroll
            for (int mi = 0; mi < 4; ++mi)
                #pragma unroll
                for (int j = 0; j < 4; ++j) {
                    int rl = wr * 64 + mi * 16 + ((lane >> 4) << 2) + j;
                    float v = accM[mi][ni][j] + sw_s[rl] * bv;
                    *(uint16_t*)(Tmn + rl * 256 + ((col * 2) ^ ((rl & 7) << 4))) =
                        (uint16_t)f2bf(v);
                }
        }
        __syncthreads();
    }

    // ---- gate GEMM: [me|mn|h](K=384) @ W_g1 ----
    f32x4 accG[4][2] = {};
    #pragma unroll 1
    for (int c = 0; c < 3; ++c) {
        const char* Ac = (c == 0) ? Tme : (c == 1) ? Tmn : Th;
        stage_b128(BTg1, 384, 0, c * 128, Bt, tid);
        __syncthreads();
        mfma128(Ac, Bt, wr, wc, lane, accG);
        __syncthreads();
    }
    {
        float bg[2], wg[2];
        #pragma unroll
        for (int ni = 0; ni < 2; ++ni) {
            int col = wc * 32 + ni * 16 + (lane & 15);
            bg[ni] = b_g1[col]; wg[ni] = Wg2[col];
        }
        #pragma unroll
        for (int mi = 0; mi < 4; ++mi)
            #pragma unroll
            for (int j = 0; j < 4; ++j) {
                float p = fmaxf(accG[mi][0][j] + bg[0], 0.f) * wg[0]
                        + fmaxf(accG[mi][1][j] + bg[1], 0.f) * wg[1];
                #pragma unroll
                for (int o = 8; o; o >>= 1) p += __shfl_xor(p, o);
                if ((lane & 15) == 0)
                    g_red[wc][wr * 64 + mi * 16 + ((lane >> 4) << 2) + j] = p;
            }
    }
    __syncthreads();
    if (tid < 128) {
        float t = g_red[0][tid] + g_red[1][tid] + g_red[2][tid] + g_red[3][tid]
                + b_g2[0];
        g_fin[tid] = 1.f / (1.f + __expf(-t));
    }
    __syncthreads();

    // M = me + g*mn  (bf16, in place of Tmn)
    {
        const int c = tid & 15;
        #pragma unroll
        for (int p = 0; p < 4; ++p) {
            int row = p * 32 + (tid >> 4);
            float g = g_fin[row];
            int sw = (row & 7) << 4;
            #pragma unroll
            for (int hh = 0; hh < 2; ++hh) {
                int off = (c * 8 + hh * 128) ^ sw;
                uint2 me2 = *(uint2*)(Tme + row * 256 + off);
                uint2 mn2 = *(uint2*)(Tmn + row * 256 + off);
                *(uint2*)(Tmn + row * 256 + off) =
                    make_uint2(comb2(me2.x, mn2.x, g), comb2(me2.y, mn2.y, g));
            }
        }
    }
    __syncthreads();

    // ---- GRU phases ----
    f32x4 aR[4][2] = {}, aZ[4][2] = {}, aGI[4][2] = {}, aGH[4][2] = {};
    stage_b128(BTcomb, 256, 0, 0, Bt, tid);   __syncthreads();
    mfma128(Tmn, Bt, wr, wc, lane, aR);       __syncthreads();
    stage_b128(BTcomb, 256, 0, 128, Bt, tid); __syncthreads();
    mfma128(Th, Bt, wr, wc, lane, aR);        __syncthreads();
    stage_b128(BTcomb, 256, 128, 0, Bt, tid); __syncthreads();
    mfma128(Tmn, Bt, wr, wc, lane, aZ);       __syncthreads();
    stage_b128(BTcomb, 256, 128, 128, Bt, tid); __syncthreads();
    mfma128(Th, Bt, wr, wc, lane, aZ);        __syncthreads();
    stage_b128(BTihn, 128, 0, 0, Bt, tid);    __syncthreads();
    mfma128(Tmn, Bt, wr, wc, lane, aGI);      __syncthreads();
    stage_b128(BThhn, 128, 0, 0, Bt, tid);    __syncthreads();
    mfma128(Th, Bt, wr, wc, lane, aGH);

    // ---- GRU epilogue (masked); maintains h_bf shadow ----
    #pragma unroll
    for (int ni = 0; ni < 2; ++ni) {
        int col = wc * 32 + ni * 16 + (lane & 15);
        float br  = b_ih[col] + b_hh[col];
        float bz  = b_ih[128 + col] + b_hh[128 + col];
        float bin = b_ih[256 + col], bhn = b_hh[256 + col];
        #pragma unroll
        for (int mi = 0; mi < 4; ++mi)
            #pragma unroll
            for (int j = 0; j < 4; ++j) {
                int node = m0 + wr * 64 + mi * 16 + ((lane >> 4) << 2) + j;
                if (node < N_NODES && cpl_cnt[node] > 0.f) {
                    float r = 1.f / (1.f + __expf(-(aR[mi][ni][j] + br)));
                    float z = 1.f / (1.f + __expf(-(aZ[mi][ni][j] + bz)));
                    float nn = tanhf(aGI[mi][ni][j] + bin + r * (aGH[mi][ni][j] + bhn));
                    size_t hb = (size_t)node * HDIM + col;
                    float hv = out_h[hb];
                    float hn = (1.f - z) * nn + z * hv;
                    out_h[hb] = hn;
                    h_bf[hb] = (uint16_t)f2bf(hn);
                }
            }
    }
}

// ---------------- gather: agg[n] = sum w_norm * h_bf[row] (champion) --------
__global__ __launch_bounds__(256)
void k_mnode_gather(const int* __restrict__ row_ptr, const int* __restrict__ csr_row,
                    const float* __restrict__ csr_w, const uint16_t* __restrict__ h_bf,
                    uint16_t* __restrict__ agg)
{
    int n = blockIdx.x * 4 + (threadIdx.x >> 6);
    if (n >= N_NODES) return;
    int lane = threadIdx.x & 63;
    int s = row_ptr[n], t = row_ptr[n + 1];
    float a0 = 0.f, a1 = 0.f;
    for (int j = s; j < t; ++j) {
        int r = csr_row[j];
        float w = csr_w[j];
        uint32_t v = *(const uint32_t*)(h_bf + (size_t)r * HDIM + lane * 2);
        a0 += w * bf2f(v & 0xffffu);
        a1 += w * bf2f(v >> 16);
    }
    *(uint32_t*)(agg + (size_t)n * HDIM + lane * 2) = f2bf(a0) | (f2bf(a1) << 16);
}

// ---------------- k_zero: counters + accumulators + m_edge + fmt detect -----
__global__ __launch_bounds__(256)
void k_zero(float* cpl_cnt, float* w_den, int* hist, int* counters,
            float* m_edge, const uint8_t* tie_raw)
{
    int gtid = blockIdx.x * 256 + threadIdx.x;
    int gstr = gridDim.x * 256;
    for (int i = gtid; i < N_NODES; i += gstr) {
        cpl_cnt[i] = 0.f; w_den[i] = 0.f; hist[i] = 0;
    }
    for (int i = gtid; i < N_NODES * HDIM / 4; i += gstr)
        ((float4*)m_edge)[i] = make_float4(0.f, 0.f, 0.f, 0.f);
    if (blockIdx.x == 0 && threadIdx.x < 64) {
        int c = 0;
        for (int k = threadIdx.x; k < 4096; k += 64)
            if ((k & 3) && tie_raw[k]) c = 1;
        unsigned long long m = __ballot(c != 0);
        if (threadIdx.x == 0) {
            counters[0] = (m != 0ull) ? 1 : 0;
            counters[1] = 0; counters[2] = 0;
        }
    }
}

// ---------------- k_hprep: h -> out_h + h_bf ----------------
__global__ __launch_bounds__(256)
void k_hprep(const float* __restrict__ h, float* __restrict__ out_h,
             uint16_t* __restrict__ h_bf)
{
    int gtid = blockIdx.x * 256 + threadIdx.x;
    int gstr = gridDim.x * 256;
    for (int i = gtid; i < N_NODES * HDIM / 4; i += gstr) {
        float4 v = ((const float4*)h)[i];
        ((float4*)out_h)[i] = v;
        *(uint2*)(h_bf + (size_t)i * 4) =
            make_uint2(f2bf(v.x) | (f2bf(v.y) << 16), f2bf(v.z) | (f2bf(v.w) << 16));
    }
}

// ---------------- k_prepw_all: all weights -> bf16 [N][K] (one launch) ------
__global__ __launch_bounds__(256)
void k_prepw_all(const float* W_er1, const float* W_er2, const float* W_nn,
                 const float* W_g1, const float* W_ih, const float* W_hh,
                 short* BTer1, short* BTer2, short* BTnn, short* BTg1,
                 short* BTcomb, short* BTihn, short* BThhn)
{
    int i = blockIdx.x * 256 + threadIdx.x;
    if (i < 384 * 256) {                       // BTer1 [256][384] <- W_er1[384][256]
        int n = i / 384, k = i % 384;
        BTer1[i] = (short)f2bf(W_er1[(size_t)k * 256 + n]);
    }
    if (i < 128 * 256) {                       // BTer2 [128][256] <- W_er2[256][128]
        int n = i / 256, k = i % 256;
        BTer2[i] = (short)f2bf(W_er2[(size_t)k * 128 + n]);
    }
    if (i < 128 * 128) {                       // BTnn [128][128] <- W_nn[128][128]
        int n = i / 128, k = i % 128;
        BTnn[i] = (short)f2bf(W_nn[(size_t)k * 128 + n]);
    }
    if (i < 128 * 384) {                       // BTg1 [128][384] <- W_g1[384][128]
        int n = i / 384, k = i % 384;
        BTg1[i] = (short)f2bf(W_g1[(size_t)k * 128 + n]);
    }
    if (i < 256 * 256) {                       // BTcomb [256][256] = [Wih_rz|Whh_rz]
        int n = i >> 8, k = i & 255;
        float v = (k < 128) ? W_ih[n * 128 + k] : W_hh[n * 128 + (k - 128)];
        BTcomb[i] = (short)f2bf(v);
    }
    if (i < 128 * 128) {                       // n-chunks (already [N][K])
        BTihn[i] = (short)f2bf(W_ih[256 * 128 + i]);
        BThhn[i] = (short)f2bf(W_hh[256 * 128 + i]);
    }
}

// ---------------- tie classification (wave-aggregated compaction) -----------
__global__ __launch_bounds__(256)
void k_tie(const void* __restrict__ tie_raw, const int* __restrict__ counters,
           const int* __restrict__ ei, float* __restrict__ cpl_cnt,
           int* __restrict__ tie_cnt, int* __restrict__ tie_list,
           int* __restrict__ tie_row, int* __restrict__ tie_col)
{
    int e = blockIdx.x * 256 + threadIdx.x;
    int fmt = counters[0];
    bool t = false; int r = 0, c = 0;
    if (e < N_EDGES)
        t = fmt ? (((const uint8_t*)tie_raw)[e] != 0)
                : (((const int*)tie_raw)[e] != 0);
    if (t) {
        r = ei[e]; c = ei[N_EDGES + e];
        atomicAdd(&cpl_cnt[r], 1.f);
        atomicAdd(&cpl_cnt[c], 1.f);
    }
    unsigned long long m = __ballot(t);
    if (m == 0ull) return;
    int lane = threadIdx.x & 63;
    int first = __ffsll((unsigned long long)m) - 1;
    int base = 0;
    if (lane == first) base = atomicAdd(tie_cnt, __popcll(m));
    base = __shfl(base, first);
    if (t) {
        int idx = base + __popcll(m & ((1ull << lane) - 1ull));
        if (idx < TIE_CAP) { tie_list[idx] = e; tie_row[idx] = r; tie_col[idx] = c; }
    }
}

__global__ __launch_bounds__(256)
void k_w(const void* __restrict__ tie_raw, const int* __restrict__ counters,
         const int* __restrict__ ei, const float* __restrict__ attr,
         const float* __restrict__ cpl_cnt, float* __restrict__ w_den,
         float* __restrict__ w_arr, int* __restrict__ hist)
{
    int e = blockIdx.x * 256 + threadIdx.x;
    if (e >= N_EDGES) return;
    int fmt = counters[0];
    bool t = fmt ? (((const uint8_t*)tie_raw)[e] != 0)
                 : (((const int*)tie_raw)[e] != 0);
    float w = 0.f;
    if (!t) {
        int c = ei[N_EDGES + e];
        if (cpl_cnt[c] > 0.f) {
            float X = fabsf(attr[(size_t)e * 10 + 1]);
            w = 1.f / sqrtf(X * X + 1e-6f);
            atomicAdd(&w_den[c], w);
            atomicAdd(&hist[c], 1);
        }
    }
    w_arr[e] = w;
}

// ---------------- CSR build ----------------
__global__ __launch_bounds__(SCAN_B)
void k_scan1(const int* __restrict__ hist, int* __restrict__ excl,
             int* __restrict__ bsum)
{
    __shared__ int s[SCAN_B];
    int t = threadIdx.x;
    int i = blockIdx.x * SCAN_B + t;
    int v = (i < N_NODES) ? hist[i] : 0;
    s[t] = v;
    __syncthreads();
    for (int o = 1; o < SCAN_B; o <<= 1) {
        int u = (t >= o) ? s[t - o] : 0;
        __syncthreads();
        s[t] += u;
        __syncthreads();
    }
    if (i < N_NODES) excl[i] = s[t] - v;
    if (t == SCAN_B - 1) bsum[blockIdx.x] = s[t];
}

__global__ void k_scan2(int* __restrict__ bsum, int* __restrict__ counters)
{
    const int NB = (N_NODES + SCAN_B - 1) / SCAN_B;
    if (threadIdx.x == 0) {
        int run = 0;
        for (int b = 0; b < NB; ++b) { int x = bsum[b]; bsum[b] = run; run += x; }
        counters[2] = run;
    }
}

__global__ __launch_bounds__(256)
void k_scan3(const int* __restrict__ excl, const int* __restrict__ bsum,
             int* __restrict__ row_ptr, int* __restrict__ cursor,
             const int* __restrict__ counters,
             const float* __restrict__ cpl_cnt, const float* __restrict__ w_den,
             float* __restrict__ deg_inv, float* __restrict__ sumw)
{
    int i = blockIdx.x * 256 + threadIdx.x;
    if (i < N_NODES) {
        int v = excl[i] + bsum[i >> 8];
        row_ptr[i] = v;
        cursor[i] = v;
        deg_inv[i] = 1.f / fmaxf(cpl_cnt[i], 1.f);
        float wd = w_den[i];
        sumw[i] = wd / (wd + 1e-6f);
    }
    if (i == N_NODES) row_ptr[N_NODES] = counters[2];
}

__global__ __launch_bounds__(256)
void k_fill(const int* __restrict__ ei, const float* __restrict__ w_arr,
            const float* __restrict__ w_den, int* __restrict__ cursor,
            int* __restrict__ csr_row, float* __restrict__ csr_w)
{
    int e = blockIdx.x * 256 + threadIdx.x;
    if (e >= N_EDGES) return;
    float w = w_arr[e];
    if (w == 0.f) return;
    int c = ei[N_EDGES + e];
    int pos = atomicAdd(&cursor[c], 1);
    csr_row[pos] = ei[e];
    csr_w[pos] = w / (w_den[c] + 1e-6f);   // normalization fused here
}

// ---------------- launch ----------------
extern "C" void kernel_launch(void* const* d_in, const int* in_sizes, int n_in,
                              void* d_out, int out_size, void* d_ws, size_t ws_size,
                              hipStream_t stream)
{
    const float* h     = (const float*)d_in[0];
    const float* e     = (const float*)d_in[1];
    const float* attr  = (const float*)d_in[2];
    const float* W_er1 = (const float*)d_in[3];
    const float* b_er1 = (const float*)d_in[4];
    const float* W_er2 = (const float*)d_in[5];
    const float* b_er2 = (const float*)d_in[6];
    const float* W_ih  = (const float*)d_in[7];
    const float* W_hh  = (const float*)d_in[8];
    const float* b_ih  = (const float*)d_in[9];
    const float* b_hh  = (const float*)d_in[10];
    const float* W_nn  = (const float*)d_in[11];
    const float* b_nn  = (const float*)d_in[12];
    const float* W_g1  = (const float*)d_in[13];
    const float* b_g1  = (const float*)d_in[14];
    const float* W_g2  = (const float*)d_in[15];
    const float* b_g2  = (const float*)d_in[16];
    const int*   ei    = (const int*)d_in[17];
    const void*  tie_raw = d_in[18];

    float* out_h = (float*)d_out;
    float* out_e = out_h + (size_t)N_NODES * HDIM;

    char* ws = (char*)d_ws;
    size_t off = 0;
    auto alloc = [&](size_t bytes) -> void* {
        void* p = ws + off;
        off = (off + bytes + 255) & ~(size_t)255;
        return p;
    };
    float* cpl_cnt = (float*)alloc((size_t)N_NODES * 4);
    float* w_den   = (float*)alloc((size_t)N_NODES * 4);
    int*   hist    = (int*)  alloc((size_t)N_NODES * 4);
    int*   counters= (int*)  alloc(256);   // [0]=fmt [1]=tie_cnt [2]=csr_total
    float* deg_inv = (float*)alloc((size_t)N_NODES * 4);
    float* sumw    = (float*)alloc((size_t)N_NODES * 4);
    float* w_arr   = (float*)alloc((size_t)N_EDGES * 4);
    int* tie_list  = (int*)alloc((size_t)TIE_CAP * 4);
    int* tie_row   = (int*)alloc((size_t)TIE_CAP * 4);
    int* tie_col   = (int*)alloc((size_t)TIE_CAP * 4);
    short* BTer1   = (short*)alloc((size_t)256 * 384 * 2);
    short* BTer2   = (short*)alloc((size_t)128 * 256 * 2);
    short* BTnn    = (short*)alloc((size_t)128 * 128 * 2);
    short* BTg1    = (short*)alloc((size_t)128 * 384 * 2);
    short* BTcomb  = (short*)alloc((size_t)256 * 256 * 2);
    short* BTihn   = (short*)alloc((size_t)128 * 128 * 2);
    short* BThhn   = (short*)alloc((size_t)128 * 128 * 2);
    uint16_t* h_bf = (uint16_t*)alloc((size_t)N_NODES * HDIM * 2);
    uint16_t* agg  = (uint16_t*)alloc((size_t)N_NODES * HDIM * 2);
    float* m_edge  = (float*)alloc((size_t)N_NODES * HDIM * 4);
    int* excl      = (int*)alloc((size_t)N_NODES * 4);
    int* bsum      = (int*)alloc(256 * 4);
    int* row_ptr   = (int*)alloc((size_t)(N_NODES + 1) * 4);
    int* cursor    = (int*)alloc((size_t)N_NODES * 4);
    int* csr_row   = (int*)alloc((size_t)N_EDGES * 4);
    float* csr_w   = (float*)alloc((size_t)N_EDGES * 4);
    if (off > ws_size) return;

    int* tie_cnt = counters + 1;

    const int EB   = N_EDGES / 256;                  // 3125
    const int GM_T = (TIE_CAP + 127) / 128;          // 344
    const int GM_N = (N_NODES + 127) / 128;          // 391
    const int NB   = (N_NODES + SCAN_B - 1) / SCAN_B;

    k_zero<<<400, 256, 0, stream>>>(cpl_cnt, w_den, hist, counters, m_edge,
                                    (const uint8_t*)tie_raw);
    hipMemcpyAsync(out_e, e, (size_t)N_EDGES * HDIM * 4,
                   hipMemcpyDeviceToDevice, stream);
    k_hprep<<<512, 256, 0, stream>>>(h, out_h, h_bf);
    k_prepw_all<<<(384 * 256 + 255) / 256, 256, 0, stream>>>(
        W_er1, W_er2, W_nn, W_g1, W_ih, W_hh,
        BTer1, BTer2, BTnn, BTg1, BTcomb, BTihn, BThhn);
    k_tie<<<EB, 256, 0, stream>>>(tie_raw, counters, ei, cpl_cnt,
                                  tie_cnt, tie_list, tie_row, tie_col);
    k_w<<<EB, 256, 0, stream>>>(tie_raw, counters, ei, attr, cpl_cnt,
                                w_den, w_arr, hist);
    k_scan1<<<NB, SCAN_B, 0, stream>>>(hist, excl, bsum);
    k_scan2<<<1, 64, 0, stream>>>(bsum, counters);
    k_scan3<<<(N_NODES + 256) / 256, 256, 0, stream>>>(
        excl, bsum, row_ptr, cursor, counters, cpl_cnt, w_den, deg_inv, sumw);
    k_fill<<<EB, 256, 0, stream>>>(ei, w_arr, w_den, cursor, csr_row, csr_w);

    for (int it = 0; it < NITER; ++it) {
        k_tie_fused<<<GM_T, 512, 0, stream>>>(
            out_e, h_bf, tie_cnt, tie_list, tie_row, tie_col,
            BTer1, BTer2, b_er1, b_er2, deg_inv, m_edge);
        k_mnode_gather<<<(N_NODES + 3) / 4, 256, 0, stream>>>(
            row_ptr, csr_row, csr_w, h_bf, agg);
        k_node_mega<<<GM_N, 512, 0, stream>>>(
            m_edge, agg, out_h, h_bf, cpl_cnt, sumw,
            BTnn, b_nn, BTg1, b_g1, W_g2, b_g2,
            BTcomb, BTihn, BThhn, b_ih, b_hh);
    }
}

// Round 10
// 911.561 us; speedup vs baseline: 1.7579x; 1.0021x over previous
//
#include <hip/hip_runtime.h>
#include <cstdint>

#define N_NODES 50000
#define N_EDGES 800000
#define HDIM    128
#define TIE_CAP 44000
#define NITER   2
#define SCAN_B  256

typedef __attribute__((ext_vector_type(8))) short bf16x8;
typedef __attribute__((ext_vector_type(4))) float f32x4;

__device__ __forceinline__ uint32_t f2bf(float f) {
    uint32_t u = __builtin_bit_cast(uint32_t, f);
    return (u + 0x7fffu + ((u >> 16) & 1u)) >> 16;   // RNE
}
__device__ __forceinline__ float bf2f(uint32_t b) {
    return __builtin_bit_cast(float, b << 16);
}
__device__ __forceinline__ uint32_t comb2(uint32_t me, uint32_t mn, float g) {
    float a0 = bf2f(me & 0xffffu) + g * bf2f(mn & 0xffffu);
    float a1 = bf2f(me >> 16)     + g * bf2f(mn >> 16);
    return f2bf(a0) | (f2bf(a1) << 16);
}

// ---- LDS tiles: [128 rows][128 bf16] = 256B rows, byte ^= (row&7)<<4 ----

__device__ __forceinline__ void stage_a128(const float* __restrict__ base,
                                           const int* __restrict__ gidx,
                                           int m0, int Mlim, char* tile, int tid)
{
    const int c = tid & 15;
    #pragma unroll
    for (int p = 0; p < 4; ++p) {
        int row = p * 32 + (tid >> 4);
        int ar = m0 + row; if (ar >= Mlim) ar = Mlim - 1;
        long g = gidx ? gidx[ar] : ar;
        const float* s = base + g * HDIM + c * 4;
        float4 v0 = *(const float4*)s;
        float4 v1 = *(const float4*)(s + 64);
        uint2 w0 = make_uint2(f2bf(v0.x) | (f2bf(v0.y) << 16),
                              f2bf(v0.z) | (f2bf(v0.w) << 16));
        uint2 w1 = make_uint2(f2bf(v1.x) | (f2bf(v1.y) << 16),
                              f2bf(v1.z) | (f2bf(v1.w) << 16));
        int sw = (row & 7) << 4;
        *(uint2*)(tile + row * 256 + ((c * 8) ^ sw)) = w0;
        *(uint2*)(tile + row * 256 + ((c * 8 + 128) ^ sw)) = w1;
    }
}

__device__ __forceinline__ void stage_bf128(const uint16_t* __restrict__ base,
                                            const int* __restrict__ gidx,
                                            int m0, int Mlim, char* tile, int tid)
{
    const int c = tid & 15;
    #pragma unroll
    for (int p = 0; p < 4; ++p) {
        int row = p * 32 + (tid >> 4);
        int ar = m0 + row; if (ar >= Mlim) ar = Mlim - 1;
        long g = gidx ? gidx[ar] : ar;
        uint4 v = *(const uint4*)(base + g * HDIM + c * 8);
        *(uint4*)(tile + row * 256 + ((c * 16) ^ ((row & 7) << 4))) = v;
    }
}

__device__ __forceinline__ void stage_b128(const short* __restrict__ BT, int ldk,
                                           int n0, int k0, char* tile, int tid)
{
    const int c = tid & 15;
    #pragma unroll
    for (int p = 0; p < 4; ++p) {
        int n = p * 32 + (tid >> 4);
        uint4 v = *(const uint4*)&BT[(size_t)(n0 + n) * ldk + k0 + c * 8];
        *(uint4*)(tile + n * 256 + ((c * 16) ^ ((n & 7) << 4))) = v;
    }
}

// one K=128 chunk: 8 waves in 2(M)x4(N); wave does 64x32 via 16x16x32 MFMA
__device__ __forceinline__ void mfma128(const char* At, const char* Bt,
                                        int wr, int wc, int lane, f32x4 acc[4][2])
{
    #pragma unroll
    for (int ks = 0; ks < 4; ++ks) {
        int kb = ks * 64 + (lane >> 4) * 16;
        bf16x8 aF[4], bF[2];
        #pragma unroll
        for (int mi = 0; mi < 4; ++mi) {
            int row = wr * 64 + mi * 16 + (lane & 15);
            aF[mi] = *(const bf16x8*)(At + row * 256 + (kb ^ ((row & 7) << 4)));
        }
        #pragma unroll
        for (int ni = 0; ni < 2; ++ni) {
            int n = wc * 32 + ni * 16 + (lane & 15);
            bF[ni] = *(const bf16x8*)(Bt + n * 256 + (kb ^ ((n & 7) << 4)));
        }
        #pragma unroll
        for (int mi = 0; mi < 4; ++mi)
            #pragma unroll
            for (int ni = 0; ni < 2; ++ni)
                acc[mi][ni] = __builtin_amdgcn_mfma_f32_16x16x32_bf16(
                    aF[mi], bF[ni], acc[mi][ni], 0, 0, 0);
    }
}

// ---------------- fused tie-edge kernel (champion) --------------------------
__global__ __launch_bounds__(512)
void k_tie_fused(float* __restrict__ out_e, const uint16_t* __restrict__ h_bf,
                 const int* __restrict__ tie_cnt_p,
                 const int* __restrict__ tie_list, const int* __restrict__ tie_row,
                 const int* __restrict__ tie_col,
                 const short* __restrict__ BTer1, const short* __restrict__ BTer2,
                 const float* __restrict__ b_er1, const float* __restrict__ b_er2,
                 const float* __restrict__ deg_inv, float* __restrict__ m_edge)
{
    int cnt = *tie_cnt_p; if (cnt > TIE_CAP) cnt = TIE_CAP;
    const int m0 = blockIdx.x * 128;
    if (m0 >= cnt) return;

    __shared__ __align__(16) char At[32 * 1024];
    __shared__ __align__(16) char B0[32 * 1024];
    __shared__ __align__(16) char B1[32 * 1024];

    const int tid = threadIdx.x, lane = tid & 63;
    const int wid = tid >> 6, wr = wid >> 2, wc = wid & 3;

    f32x4 acc0[4][2] = {}, acc1[4][2] = {};
    #pragma unroll 1
    for (int c = 0; c < 3; ++c) {
        if (c == 0) stage_a128(out_e, tie_list, m0, cnt, At, tid);
        else        stage_bf128(h_bf, (c == 1) ? tie_row : tie_col, m0, cnt, At, tid);
        stage_b128(BTer1, 384, 0,   c * 128, B0, tid);
        stage_b128(BTer1, 384, 128, c * 128, B1, tid);
        __syncthreads();
        mfma128(At, B0, wr, wc, lane, acc0);
        mfma128(At, B1, wr, wc, lane, acc1);
        __syncthreads();
    }

    // epilogue1: relu(acc+b) -> bf16 C1 tiles (At = cols 0-127, B0 = 128-255)
    #pragma unroll
    for (int half = 0; half < 2; ++half) {
        char* Ct = half ? B0 : At;
        #pragma unroll
        for (int ni = 0; ni < 2; ++ni) {
            int col = wc * 32 + ni * 16 + (lane & 15);
            float bv = b_er1[half * 128 + col];
            #pragma unroll
            for (int mi = 0; mi < 4; ++mi)
                #pragma unroll
                for (int j = 0; j < 4; ++j) {
                    int rl = wr * 64 + mi * 16 + ((lane >> 4) << 2) + j;
                    float v = fmaxf((half ? acc1 : acc0)[mi][ni][j] + bv, 0.f);
                    *(uint16_t*)(Ct + rl * 256 + ((col * 2) ^ ((rl & 7) << 4))) =
                        (uint16_t)f2bf(v);
                }
        }
    }
    stage_b128(BTer2, 256, 0, 0, B1, tid);
    __syncthreads();
    f32x4 acc2[4][2] = {};
    mfma128(At, B1, wr, wc, lane, acc2);
    __syncthreads();
    stage_b128(BTer2, 256, 0, 128, B1, tid);
    __syncthreads();
    mfma128(B0, B1, wr, wc, lane, acc2);

    // epilogue2: e_work += eref; scatter v*deg_inv into m_edge
    int col0 = wc * 32 + (lane & 15);
    float bv0 = b_er2[col0], bv1 = b_er2[col0 + 16];
    #pragma unroll
    for (int mi = 0; mi < 4; ++mi) {
        #pragma unroll
        for (int j = 0; j < 4; ++j) {
            int i = m0 + wr * 64 + mi * 16 + ((lane >> 4) << 2) + j;
            if (i < cnt) {
                int e = tie_list[i], r = tie_row[i], cc = tie_col[i];
                float dr = deg_inv[r], dc = deg_inv[cc];
                #pragma unroll
                for (int ni = 0; ni < 2; ++ni) {
                    int col = col0 + ni * 16;
                    float er = acc2[mi][ni][j] + (ni ? bv1 : bv0);
                    size_t eb = (size_t)e * HDIM + col;
                    float v = out_e[eb] + er;
                    out_e[eb] = v;
                    atomicAdd(&m_edge[(size_t)r * HDIM + col], v * dr);
                    atomicAdd(&m_edge[(size_t)cc * HDIM + col], v * dc);
                }
            }
        }
    }
}

// ---------------- fused node kernel (champion + self-zero) ------------------
__global__ __launch_bounds__(512)
void k_node_mega(float* __restrict__ m_edge, const uint16_t* __restrict__ agg,
                 float* __restrict__ out_h, uint16_t* __restrict__ h_bf,
                 const float* __restrict__ cpl_cnt, const float* __restrict__ sumw,
                 const short* __restrict__ BTnn, const float* __restrict__ b_nn,
                 const short* __restrict__ BTg1, const float* __restrict__ b_g1,
                 const float* __restrict__ Wg2, const float* __restrict__ b_g2,
                 const short* __restrict__ BTcomb,
                 const short* __restrict__ BTihn, const short* __restrict__ BThhn,
                 const float* __restrict__ b_ih, const float* __restrict__ b_hh)
{
    const int m0 = blockIdx.x * 128;
    __shared__ __align__(16) char Tme[32 * 1024];
    __shared__ __align__(16) char Tmn[32 * 1024];   // agg -> m_node -> M
    __shared__ __align__(16) char Th [32 * 1024];
    __shared__ __align__(16) char Bt [32 * 1024];
    __shared__ float g_red[4][128];
    __shared__ float g_fin[128];
    __shared__ float sw_s[128];

    const int tid = threadIdx.x, lane = tid & 63;
    const int wid = tid >> 6, wr = wid >> 2, wc = wid & 3;

    stage_a128(m_edge, nullptr, m0, N_NODES, Tme, tid);
    stage_bf128(agg,   nullptr, m0, N_NODES, Tmn, tid);
    stage_bf128(h_bf,  nullptr, m0, N_NODES, Th,  tid);
    stage_b128(BTnn, 128, 0, 0, Bt, tid);
    if (tid < 128) {
        int n = m0 + tid; if (n >= N_NODES) n = N_NODES - 1;
        sw_s[tid] = sumw[n];
    }
    __syncthreads();

    // self-zero own m_edge rows for the NEXT iteration (Tme already staged)
    {
        int lim = (N_NODES - m0 < 128 ? N_NODES - m0 : 128) * HDIM / 4;
        float4* mp = (float4*)(m_edge + (size_t)m0 * HDIM);
        for (int i2 = tid; i2 < lim; i2 += 512)
            mp[i2] = make_float4(0.f, 0.f, 0.f, 0.f);
    }

    // ---- phase 0: m_node = agg @ W_nn + sumw*b_nn  -> bf16 into Tmn ----
    {
        f32x4 accM[4][2] = {};
        mfma128(Tmn, Bt, wr, wc, lane, accM);
        __syncthreads();
        #pragma unroll
        for (int ni = 0; ni < 2; ++ni) {
            int col = wc * 32 + ni * 16 + (lane & 15);
            float bv = b_nn[col];
            #pragma unroll
            for (int mi = 0; mi < 4; ++mi)
                #pragma unroll
                for (int j = 0; j < 4; ++j) {
                    int rl = wr * 64 + mi * 16 + ((lane >> 4) << 2) + j;
                    float v = accM[mi][ni][j] + sw_s[rl] * bv;
                    *(uint16_t*)(Tmn + rl * 256 + ((col * 2) ^ ((rl & 7) << 4))) =
                        (uint16_t)f2bf(v);
                }
        }
        __syncthreads();
    }

    // ---- gate GEMM: [me|mn|h](K=384) @ W_g1 ----
    f32x4 accG[4][2] = {};
    #pragma unroll 1
    for (int c = 0; c < 3; ++c) {
        const char* Ac = (c == 0) ? Tme : (c == 1) ? Tmn : Th;
        stage_b128(BTg1, 384, 0, c * 128, Bt, tid);
        __syncthreads();
        mfma128(Ac, Bt, wr, wc, lane, accG);
        __syncthreads();
    }
    {
        float bg[2], wg[2];
        #pragma unroll
        for (int ni = 0; ni < 2; ++ni) {
            int col = wc * 32 + ni * 16 + (lane & 15);
            bg[ni] = b_g1[col]; wg[ni] = Wg2[col];
        }
        #pragma unroll
        for (int mi = 0; mi < 4; ++mi)
            #pragma unroll
            for (int j = 0; j < 4; ++j) {
                float p = fmaxf(accG[mi][0][j] + bg[0], 0.f) * wg[0]
                        + fmaxf(accG[mi][1][j] + bg[1], 0.f) * wg[1];
                #pragma unroll
                for (int o = 8; o; o >>= 1) p += __shfl_xor(p, o);
                if ((lane & 15) == 0)
                    g_red[wc][wr * 64 + mi * 16 + ((lane >> 4) << 2) + j] = p;
            }
    }
    __syncthreads();
    if (tid < 128) {
        float t = g_red[0][tid] + g_red[1][tid] + g_red[2][tid] + g_red[3][tid]
                + b_g2[0];
        g_fin[tid] = 1.f / (1.f + __expf(-t));
    }
    __syncthreads();

    // M = me + g*mn  (bf16, in place of Tmn)
    {
        const int c = tid & 15;
        #pragma unroll
        for (int p = 0; p < 4; ++p) {
            int row = p * 32 + (tid >> 4);
            float g = g_fin[row];
            int sw = (row & 7) << 4;
            #pragma unroll
            for (int hh = 0; hh < 2; ++hh) {
                int off = (c * 8 + hh * 128) ^ sw;
                uint2 me2 = *(uint2*)(Tme + row * 256 + off);
                uint2 mn2 = *(uint2*)(Tmn + row * 256 + off);
                *(uint2*)(Tmn + row * 256 + off) =
                    make_uint2(comb2(me2.x, mn2.x, g), comb2(me2.y, mn2.y, g));
            }
        }
    }
    __syncthreads();

    // ---- GRU phases ----
    f32x4 aR[4][2] = {}, aZ[4][2] = {}, aGI[4][2] = {}, aGH[4][2] = {};
    stage_b128(BTcomb, 256, 0, 0, Bt, tid);   __syncthreads();
    mfma128(Tmn, Bt, wr, wc, lane, aR);       __syncthreads();
    stage_b128(BTcomb, 256, 0, 128, Bt, tid); __syncthreads();
    mfma128(Th, Bt, wr, wc, lane, aR);        __syncthreads();
    stage_b128(BTcomb, 256, 128, 0, Bt, tid); __syncthreads();
    mfma128(Tmn, Bt, wr, wc, lane, aZ);       __syncthreads();
    stage_b128(BTcomb, 256, 128, 128, Bt, tid); __syncthreads();
    mfma128(Th, Bt, wr, wc, lane, aZ);        __syncthreads();
    stage_b128(BTihn, 128, 0, 0, Bt, tid);    __syncthreads();
    mfma128(Tmn, Bt, wr, wc, lane, aGI);      __syncthreads();
    stage_b128(BThhn, 128, 0, 0, Bt, tid);    __syncthreads();
    mfma128(Th, Bt, wr, wc, lane, aGH);

    // ---- GRU epilogue (masked); maintains h_bf shadow ----
    #pragma unroll
    for (int ni = 0; ni < 2; ++ni) {
        int col = wc * 32 + ni * 16 + (lane & 15);
        float br  = b_ih[col] + b_hh[col];
        float bz  = b_ih[128 + col] + b_hh[128 + col];
        float bin = b_ih[256 + col], bhn = b_hh[256 + col];
        #pragma unroll
        for (int mi = 0; mi < 4; ++mi)
            #pragma unroll
            for (int j = 0; j < 4; ++j) {
                int node = m0 + wr * 64 + mi * 16 + ((lane >> 4) << 2) + j;
                if (node < N_NODES && cpl_cnt[node] > 0.f) {
                    float r = 1.f / (1.f + __expf(-(aR[mi][ni][j] + br)));
                    float z = 1.f / (1.f + __expf(-(aZ[mi][ni][j] + bz)));
                    float nn = tanhf(aGI[mi][ni][j] + bin + r * (aGH[mi][ni][j] + bhn));
                    size_t hb = (size_t)node * HDIM + col;
                    float hv = out_h[hb];
                    float hn = (1.f - z) * nn + z * hv;
                    out_h[hb] = hn;
                    h_bf[hb] = (uint16_t)f2bf(hn);
                }
            }
    }
}

// ---------------- gather: agg[n] = sum w_norm * h_bf[row] -------------------
__global__ __launch_bounds__(256)
void k_mnode_gather(const int* __restrict__ row_ptr, const int* __restrict__ csr_row,
                    const float* __restrict__ csr_w, const uint16_t* __restrict__ h_bf,
                    uint16_t* __restrict__ agg)
{
    int n = blockIdx.x * 4 + (threadIdx.x >> 6);
    if (n >= N_NODES) return;
    int lane = threadIdx.x & 63;
    int s = row_ptr[n], t = row_ptr[n + 1];
    float a0 = 0.f, a1 = 0.f;
    for (int j = s; j < t; ++j) {
        int r = csr_row[j];
        float w = csr_w[j];
        uint32_t v = *(const uint32_t*)(h_bf + (size_t)r * HDIM + lane * 2);
        a0 += w * bf2f(v & 0xffffu);
        a1 += w * bf2f(v >> 16);
    }
    *(uint32_t*)(agg + (size_t)n * HDIM + lane * 2) = f2bf(a0) | (f2bf(a1) << 16);
}

// ---------------- k_init: block-partitioned prep (incl. e-copy) -------------
// blocks [0,2048)  : e -> out_e copy (bulk HBM job)
// blocks [2048,2304): h -> out_h + h_bf
// blocks [2304,2560): m_edge zero
// blocks [2560,2624): cpl_cnt / w_den / hist zero
// blocks [2624,2752): weight -> bf16 transposes
// block  2752       : fmt detect + counters
#define INIT_BLOCKS 2753

__global__ __launch_bounds__(256)
void k_init(const float* __restrict__ e, float* __restrict__ out_e,
            const float* __restrict__ h, float* __restrict__ out_h,
            uint16_t* __restrict__ h_bf, float* __restrict__ m_edge,
            float* __restrict__ cpl_cnt, float* __restrict__ w_den,
            int* __restrict__ hist, int* __restrict__ counters,
            const uint8_t* __restrict__ tie_raw,
            const float* __restrict__ W_er1, const float* __restrict__ W_er2,
            const float* __restrict__ W_nn, const float* __restrict__ W_g1,
            const float* __restrict__ W_ih, const float* __restrict__ W_hh,
            short* __restrict__ BTer1, short* __restrict__ BTer2,
            short* __restrict__ BTnn, short* __restrict__ BTg1,
            short* __restrict__ BTcomb, short* __restrict__ BTihn,
            short* __restrict__ BThhn)
{
    const int b = blockIdx.x, t = threadIdx.x;
    if (b < 2048) {
        const float4* src = (const float4*)e;
        float4* dst = (float4*)out_e;
        for (int i = b * 256 + t; i < N_EDGES * HDIM / 4; i += 2048 * 256)
            dst[i] = src[i];
    } else if (b < 2304) {
        for (int i = (b - 2048) * 256 + t; i < N_NODES * HDIM / 4; i += 256 * 256) {
            float4 v = ((const float4*)h)[i];
            ((float4*)out_h)[i] = v;
            *(uint2*)(h_bf + (size_t)i * 4) =
                make_uint2(f2bf(v.x) | (f2bf(v.y) << 16),
                           f2bf(v.z) | (f2bf(v.w) << 16));
        }
    } else if (b < 2560) {
        for (int i = (b - 2304) * 256 + t; i < N_NODES * HDIM / 4; i += 256 * 256)
            ((float4*)m_edge)[i] = make_float4(0.f, 0.f, 0.f, 0.f);
    } else if (b < 2624) {
        for (int i = (b - 2560) * 256 + t; i < N_NODES; i += 64 * 256) {
            cpl_cnt[i] = 0.f; w_den[i] = 0.f; hist[i] = 0;
        }
    } else if (b < 2752) {
        for (int i = (b - 2624) * 256 + t; i < 384 * 256; i += 128 * 256) {
            {   int n = i / 384, k = i % 384;
                BTer1[i] = (short)f2bf(W_er1[(size_t)k * 256 + n]); }
            if (i < 128 * 256) {
                int n = i / 256, k = i % 256;
                BTer2[i] = (short)f2bf(W_er2[(size_t)k * 128 + n]); }
            if (i < 128 * 128) {
                int n = i / 128, k = i % 128;
                BTnn[i] = (short)f2bf(W_nn[(size_t)k * 128 + n]); }
            if (i < 128 * 384) {
                int n = i / 384, k = i % 384;
                BTg1[i] = (short)f2bf(W_g1[(size_t)k * 128 + n]); }
            if (i < 256 * 256) {
                int n = i >> 8, k = i & 255;
                float v = (k < 128) ? W_ih[n * 128 + k] : W_hh[n * 128 + (k - 128)];
                BTcomb[i] = (short)f2bf(v); }
            if (i < 128 * 128) {
                BTihn[i] = (short)f2bf(W_ih[256 * 128 + i]);
                BThhn[i] = (short)f2bf(W_hh[256 * 128 + i]); }
        }
    } else {
        if (t < 64) {
            int c = 0;
            for (int k = t; k < 4096; k += 64)
                if ((k & 3) && tie_raw[k]) c = 1;
            unsigned long long m = __ballot(c != 0);
            if (t == 0) {
                counters[0] = (m != 0ull) ? 1 : 0;
                counters[1] = 0; counters[2] = 0;
            }
        }
    }
}

// ---------------- tie classification (wave-aggregated compaction) -----------
__global__ __launch_bounds__(256)
void k_tie(const void* __restrict__ tie_raw, const int* __restrict__ counters,
           const int* __restrict__ ei, float* __restrict__ cpl_cnt,
           int* __restrict__ tie_cnt, int* __restrict__ tie_list,
           int* __restrict__ tie_row, int* __restrict__ tie_col)
{
    int e = blockIdx.x * 256 + threadIdx.x;
    int fmt = counters[0];
    bool t = false; int r = 0, c = 0;
    if (e < N_EDGES)
        t = fmt ? (((const uint8_t*)tie_raw)[e] != 0)
                : (((const int*)tie_raw)[e] != 0);
    if (t) {
        r = ei[e]; c = ei[N_EDGES + e];
        atomicAdd(&cpl_cnt[r], 1.f);
        atomicAdd(&cpl_cnt[c], 1.f);
    }
    unsigned long long m = __ballot(t);
    if (m == 0ull) return;
    int lane = threadIdx.x & 63;
    int first = __ffsll((unsigned long long)m) - 1;
    int base = 0;
    if (lane == first) base = atomicAdd(tie_cnt, __popcll(m));
    base = __shfl(base, first);
    if (t) {
        int idx = base + __popcll(m & ((1ull << lane) - 1ull));
        if (idx < TIE_CAP) { tie_list[idx] = e; tie_row[idx] = r; tie_col[idx] = c; }
    }
}

__global__ __launch_bounds__(256)
void k_w(const void* __restrict__ tie_raw, const int* __restrict__ counters,
         const int* __restrict__ ei, const float* __restrict__ attr,
         const float* __restrict__ cpl_cnt, float* __restrict__ w_den,
         float* __restrict__ w_arr, int* __restrict__ hist)
{
    int e = blockIdx.x * 256 + threadIdx.x;
    if (e >= N_EDGES) return;
    int fmt = counters[0];
    bool t = fmt ? (((const uint8_t*)tie_raw)[e] != 0)
                 : (((const int*)tie_raw)[e] != 0);
    float w = 0.f;
    if (!t) {
        int c = ei[N_EDGES + e];
        if (cpl_cnt[c] > 0.f) {
            float X = fabsf(attr[(size_t)e * 10 + 1]);
            w = 1.f / sqrtf(X * X + 1e-6f);
            atomicAdd(&w_den[c], w);
            atomicAdd(&hist[c], 1);
        }
    }
    w_arr[e] = w;
}

// ---------------- CSR build ----------------
__global__ __launch_bounds__(SCAN_B)
void k_scan1(const int* __restrict__ hist, int* __restrict__ excl,
             int* __restrict__ bsum)
{
    __shared__ int s[SCAN_B];
    int t = threadIdx.x;
    int i = blockIdx.x * SCAN_B + t;
    int v = (i < N_NODES) ? hist[i] : 0;
    s[t] = v;
    __syncthreads();
    for (int o = 1; o < SCAN_B; o <<= 1) {
        int u = (t >= o) ? s[t - o] : 0;
        __syncthreads();
        s[t] += u;
        __syncthreads();
    }
    if (i < N_NODES) excl[i] = s[t] - v;
    if (t == SCAN_B - 1) bsum[blockIdx.x] = s[t];
}

__global__ void k_scan2(int* __restrict__ bsum, int* __restrict__ counters)
{
    const int NB = (N_NODES + SCAN_B - 1) / SCAN_B;
    if (threadIdx.x == 0) {
        int run = 0;
        for (int b = 0; b < NB; ++b) { int x = bsum[b]; bsum[b] = run; run += x; }
        counters[2] = run;
    }
}

__global__ __launch_bounds__(256)
void k_scan3(const int* __restrict__ excl, const int* __restrict__ bsum,
             int* __restrict__ row_ptr, int* __restrict__ cursor,
             const int* __restrict__ counters,
             const float* __restrict__ cpl_cnt, const float* __restrict__ w_den,
             float* __restrict__ deg_inv, float* __restrict__ sumw)
{
    int i = blockIdx.x * 256 + threadIdx.x;
    if (i < N_NODES) {
        int v = excl[i] + bsum[i >> 8];
        row_ptr[i] = v;
        cursor[i] = v;
        deg_inv[i] = 1.f / fmaxf(cpl_cnt[i], 1.f);
        float wd = w_den[i];
        sumw[i] = wd / (wd + 1e-6f);
    }
    if (i == N_NODES) row_ptr[N_NODES] = counters[2];
}

__global__ __launch_bounds__(256)
void k_fill(const int* __restrict__ ei, const float* __restrict__ w_arr,
            const float* __restrict__ w_den, int* __restrict__ cursor,
            int* __restrict__ csr_row, float* __restrict__ csr_w)
{
    int e = blockIdx.x * 256 + threadIdx.x;
    if (e >= N_EDGES) return;
    float w = w_arr[e];
    if (w == 0.f) return;
    int c = ei[N_EDGES + e];
    int pos = atomicAdd(&cursor[c], 1);
    csr_row[pos] = ei[e];
    csr_w[pos] = w / (w_den[c] + 1e-6f);
}

// ---------------- launch ----------------
extern "C" void kernel_launch(void* const* d_in, const int* in_sizes, int n_in,
                              void* d_out, int out_size, void* d_ws, size_t ws_size,
                              hipStream_t stream)
{
    const float* h     = (const float*)d_in[0];
    const float* e     = (const float*)d_in[1];
    const float* attr  = (const float*)d_in[2];
    const float* W_er1 = (const float*)d_in[3];
    const float* b_er1 = (const float*)d_in[4];
    const float* W_er2 = (const float*)d_in[5];
    const float* b_er2 = (const float*)d_in[6];
    const float* W_ih  = (const float*)d_in[7];
    const float* W_hh  = (const float*)d_in[8];
    const float* b_ih  = (const float*)d_in[9];
    const float* b_hh  = (const float*)d_in[10];
    const float* W_nn  = (const float*)d_in[11];
    const float* b_nn  = (const float*)d_in[12];
    const float* W_g1  = (const float*)d_in[13];
    const float* b_g1  = (const float*)d_in[14];
    const float* W_g2  = (const float*)d_in[15];
    const float* b_g2  = (const float*)d_in[16];
    const int*   ei    = (const int*)d_in[17];
    const void*  tie_raw = d_in[18];

    float* out_h = (float*)d_out;
    float* out_e = out_h + (size_t)N_NODES * HDIM;

    char* ws = (char*)d_ws;
    size_t off = 0;
    auto alloc = [&](size_t bytes) -> void* {
        void* p = ws + off;
        off = (off + bytes + 255) & ~(size_t)255;
        return p;
    };
    float* cpl_cnt = (float*)alloc((size_t)N_NODES * 4);
    float* w_den   = (float*)alloc((size_t)N_NODES * 4);
    int*   hist    = (int*)  alloc((size_t)N_NODES * 4);
    int*   counters= (int*)  alloc(256);   // [0]=fmt [1]=tie_cnt [2]=csr_total
    float* deg_inv = (float*)alloc((size_t)N_NODES * 4);
    float* sumw    = (float*)alloc((size_t)N_NODES * 4);
    float* w_arr   = (float*)alloc((size_t)N_EDGES * 4);
    int* tie_list  = (int*)alloc((size_t)TIE_CAP * 4);
    int* tie_row   = (int*)alloc((size_t)TIE_CAP * 4);
    int* tie_col   = (int*)alloc((size_t)TIE_CAP * 4);
    short* BTer1   = (short*)alloc((size_t)256 * 384 * 2);
    short* BTer2   = (short*)alloc((size_t)128 * 256 * 2);
    short* BTnn    = (short*)alloc((size_t)128 * 128 * 2);
    short* BTg1    = (short*)alloc((size_t)128 * 384 * 2);
    short* BTcomb  = (short*)alloc((size_t)256 * 256 * 2);
    short* BTihn   = (short*)alloc((size_t)128 * 128 * 2);
    short* BThhn   = (short*)alloc((size_t)128 * 128 * 2);
    uint16_t* h_bf = (uint16_t*)alloc((size_t)N_NODES * HDIM * 2);
    uint16_t* agg  = (uint16_t*)alloc((size_t)N_NODES * HDIM * 2);
    float* m_edge  = (float*)alloc((size_t)N_NODES * HDIM * 4);
    int* excl      = (int*)alloc((size_t)N_NODES * 4);
    int* bsum      = (int*)alloc(256 * 4);
    int* row_ptr   = (int*)alloc((size_t)(N_NODES + 1) * 4);
    int* cursor    = (int*)alloc((size_t)N_NODES * 4);
    int* csr_row   = (int*)alloc((size_t)N_EDGES * 4);
    float* csr_w   = (float*)alloc((size_t)N_EDGES * 4);
    if (off > ws_size) return;

    int* tie_cnt = counters + 1;

    const int EB   = N_EDGES / 256;                  // 3125
    const int GM_T = (TIE_CAP + 127) / 128;          // 344
    const int GM_N = (N_NODES + 127) / 128;          // 391
    const int NB   = (N_NODES + SCAN_B - 1) / SCAN_B;

    k_init<<<INIT_BLOCKS, 256, 0, stream>>>(
        e, out_e, h, out_h, h_bf, m_edge, cpl_cnt, w_den, hist, counters,
        (const uint8_t*)tie_raw,
        W_er1, W_er2, W_nn, W_g1, W_ih, W_hh,
        BTer1, BTer2, BTnn, BTg1, BTcomb, BTihn, BThhn);
    k_tie<<<EB, 256, 0, stream>>>(tie_raw, counters, ei, cpl_cnt,
                                  tie_cnt, tie_list, tie_row, tie_col);
    k_w<<<EB, 256, 0, stream>>>(tie_raw, counters, ei, attr, cpl_cnt,
                                w_den, w_arr, hist);
    k_scan1<<<NB, SCAN_B, 0, stream>>>(hist, excl, bsum);
    k_scan2<<<1, 64, 0, stream>>>(bsum, counters);
    k_scan3<<<(N_NODES + 256) / 256, 256, 0, stream>>>(
        excl, bsum, row_ptr, cursor, counters, cpl_cnt, w_den, deg_inv, sumw);
    k_fill<<<EB, 256, 0, stream>>>(ei, w_arr, w_den, cursor, csr_row, csr_w);

    for (int it = 0; it < NITER; ++it) {
        k_tie_fused<<<GM_T, 512, 0, stream>>>(
            out_e, h_bf, tie_cnt, tie_list, tie_row, tie_col,
            BTer1, BTer2, b_er1, b_er2, deg_inv, m_edge);
        k_mnode_gather<<<(N_NODES + 3) / 4, 256, 0, stream>>>(
            row_ptr, csr_row, csr_w, h_bf, agg);
        k_node_mega<<<GM_N, 512, 0, stream>>>(
            m_edge, agg, out_h, h_bf, cpl_cnt, sumw,
            BTnn, b_nn, BTg1, b_g1, W_g2, b_g2,
            BTcomb, BTihn, BThhn, b_ih, b_hh);
    }
}

// Round 11
// 843.844 us; speedup vs baseline: 1.8990x; 1.0802x over previous
//
#include <hip/hip_runtime.h>
#include <cstdint>

#define N_NODES 50000
#define N_EDGES 800000
#define HDIM    128
#define TIE_CAP 44000
#define NITER   2
#define SCAN_B  256
#define EB_CONST 3125            // N_EDGES/256
#define TB_CONST 172             // ceil(TIE_CAP/256)

typedef __attribute__((ext_vector_type(8))) short bf16x8;
typedef __attribute__((ext_vector_type(4))) float f32x4;

__device__ __forceinline__ uint32_t f2bf(float f) {
    uint32_t u = __builtin_bit_cast(uint32_t, f);
    return (u + 0x7fffu + ((u >> 16) & 1u)) >> 16;   // RNE
}
__device__ __forceinline__ float bf2f(uint32_t b) {
    return __builtin_bit_cast(float, b << 16);
}
__device__ __forceinline__ uint32_t comb2(uint32_t me, uint32_t mn, float g) {
    float a0 = bf2f(me & 0xffffu) + g * bf2f(mn & 0xffffu);
    float a1 = bf2f(me >> 16)     + g * bf2f(mn >> 16);
    return f2bf(a0) | (f2bf(a1) << 16);
}

// ---- LDS tiles: [128 rows][128 bf16] = 256B rows, byte ^= (row&7)<<4 ----

__device__ __forceinline__ void stage_a128(const float* __restrict__ base,
                                           const int* __restrict__ gidx,
                                           int m0, int Mlim, char* tile, int tid)
{
    const int c = tid & 15;
    #pragma unroll
    for (int p = 0; p < 4; ++p) {
        int row = p * 32 + (tid >> 4);
        int ar = m0 + row; if (ar >= Mlim) ar = Mlim - 1;
        long g = gidx ? gidx[ar] : ar;
        const float* s = base + g * HDIM + c * 4;
        float4 v0 = *(const float4*)s;
        float4 v1 = *(const float4*)(s + 64);
        uint2 w0 = make_uint2(f2bf(v0.x) | (f2bf(v0.y) << 16),
                              f2bf(v0.z) | (f2bf(v0.w) << 16));
        uint2 w1 = make_uint2(f2bf(v1.x) | (f2bf(v1.y) << 16),
                              f2bf(v1.z) | (f2bf(v1.w) << 16));
        int sw = (row & 7) << 4;
        *(uint2*)(tile + row * 256 + ((c * 8) ^ sw)) = w0;
        *(uint2*)(tile + row * 256 + ((c * 8 + 128) ^ sw)) = w1;
    }
}

__device__ __forceinline__ void stage_bf128(const uint16_t* __restrict__ base,
                                            const int* __restrict__ gidx,
                                            int m0, int Mlim, char* tile, int tid)
{
    const int c = tid & 15;
    #pragma unroll
    for (int p = 0; p < 4; ++p) {
        int row = p * 32 + (tid >> 4);
        int ar = m0 + row; if (ar >= Mlim) ar = Mlim - 1;
        long g = gidx ? gidx[ar] : ar;
        uint4 v = *(const uint4*)(base + g * HDIM + c * 8);
        *(uint4*)(tile + row * 256 + ((c * 16) ^ ((row & 7) << 4))) = v;
    }
}

__device__ __forceinline__ void stage_b128(const short* __restrict__ BT, int ldk,
                                           int n0, int k0, char* tile, int tid)
{
    const int c = tid & 15;
    #pragma unroll
    for (int p = 0; p < 4; ++p) {
        int n = p * 32 + (tid >> 4);
        uint4 v = *(const uint4*)&BT[(size_t)(n0 + n) * ldk + k0 + c * 8];
        *(uint4*)(tile + n * 256 + ((c * 16) ^ ((n & 7) << 4))) = v;
    }
}

// one K=128 chunk: 8 waves in 2(M)x4(N); wave does 64x32 via 16x16x32 MFMA
__device__ __forceinline__ void mfma128(const char* At, const char* Bt,
                                        int wr, int wc, int lane, f32x4 acc[4][2])
{
    #pragma unroll
    for (int ks = 0; ks < 4; ++ks) {
        int kb = ks * 64 + (lane >> 4) * 16;
        bf16x8 aF[4], bF[2];
        #pragma unroll
        for (int mi = 0; mi < 4; ++mi) {
            int row = wr * 64 + mi * 16 + (lane & 15);
            aF[mi] = *(const bf16x8*)(At + row * 256 + (kb ^ ((row & 7) << 4)));
        }
        #pragma unroll
        for (int ni = 0; ni < 2; ++ni) {
            int n = wc * 32 + ni * 16 + (lane & 15);
            bF[ni] = *(const bf16x8*)(Bt + n * 256 + (kb ^ ((n & 7) << 4)));
        }
        #pragma unroll
        for (int mi = 0; mi < 4; ++mi)
            #pragma unroll
            for (int ni = 0; ni < 2; ++ni)
                acc[mi][ni] = __builtin_amdgcn_mfma_f32_16x16x32_bf16(
                    aF[mi], bF[ni], acc[mi][ni], 0, 0, 0);
    }
}

// ---------------- fused tie-edge kernel: L1 -> relu -> L2 -> e update -------
__global__ __launch_bounds__(512)
void k_tie_fused(float* __restrict__ out_e, const uint16_t* __restrict__ h_bf,
                 const int* __restrict__ tie_cnt_p,
                 const int* __restrict__ tie_list, const int* __restrict__ tie_row,
                 const int* __restrict__ tie_col,
                 const short* __restrict__ BTer1, const short* __restrict__ BTer2,
                 const float* __restrict__ b_er1, const float* __restrict__ b_er2)
{
    int cnt = *tie_cnt_p; if (cnt > TIE_CAP) cnt = TIE_CAP;
    const int m0 = blockIdx.x * 128;
    if (m0 >= cnt) return;

    __shared__ __align__(16) char At[32 * 1024];
    __shared__ __align__(16) char B0[32 * 1024];
    __shared__ __align__(16) char B1[32 * 1024];

    const int tid = threadIdx.x, lane = tid & 63;
    const int wid = tid >> 6, wr = wid >> 2, wc = wid & 3;

    f32x4 acc0[4][2] = {}, acc1[4][2] = {};
    #pragma unroll 1
    for (int c = 0; c < 3; ++c) {
        if (c == 0) stage_a128(out_e, tie_list, m0, cnt, At, tid);
        else        stage_bf128(h_bf, (c == 1) ? tie_row : tie_col, m0, cnt, At, tid);
        stage_b128(BTer1, 384, 0,   c * 128, B0, tid);
        stage_b128(BTer1, 384, 128, c * 128, B1, tid);
        __syncthreads();
        mfma128(At, B0, wr, wc, lane, acc0);
        mfma128(At, B1, wr, wc, lane, acc1);
        __syncthreads();
    }

    // epilogue1: relu(acc+b) -> bf16 C1 tiles (At = cols 0-127, B0 = 128-255)
    #pragma unroll
    for (int half = 0; half < 2; ++half) {
        char* Ct = half ? B0 : At;
        #pragma unroll
        for (int ni = 0; ni < 2; ++ni) {
            int col = wc * 32 + ni * 16 + (lane & 15);
            float bv = b_er1[half * 128 + col];
            #pragma unroll
            for (int mi = 0; mi < 4; ++mi)
                #pragma unroll
                for (int j = 0; j < 4; ++j) {
                    int rl = wr * 64 + mi * 16 + ((lane >> 4) << 2) + j;
                    float v = fmaxf((half ? acc1 : acc0)[mi][ni][j] + bv, 0.f);
                    *(uint16_t*)(Ct + rl * 256 + ((col * 2) ^ ((rl & 7) << 4))) =
                        (uint16_t)f2bf(v);
                }
        }
    }
    stage_b128(BTer2, 256, 0, 0, B1, tid);
    __syncthreads();
    f32x4 acc2[4][2] = {};
    mfma128(At, B1, wr, wc, lane, acc2);
    __syncthreads();
    stage_b128(BTer2, 256, 0, 128, B1, tid);
    __syncthreads();
    mfma128(B0, B1, wr, wc, lane, acc2);

    // epilogue2: e_work += eref (no atomics; m_edge now built by k_gather)
    int col0 = wc * 32 + (lane & 15);
    float bv0 = b_er2[col0], bv1 = b_er2[col0 + 16];
    #pragma unroll
    for (int mi = 0; mi < 4; ++mi) {
        #pragma unroll
        for (int j = 0; j < 4; ++j) {
            int i = m0 + wr * 64 + mi * 16 + ((lane >> 4) << 2) + j;
            if (i < cnt) {
                int e = tie_list[i];
                #pragma unroll
                for (int ni = 0; ni < 2; ++ni) {
                    int col = col0 + ni * 16;
                    size_t eb = (size_t)e * HDIM + col;
                    out_e[eb] += acc2[mi][ni][j] + (ni ? bv1 : bv0);
                }
            }
        }
    }
}

// ---------------- gather: agg + m_edge (tie-CSR), per node ------------------
__global__ __launch_bounds__(256)
void k_gather(const int* __restrict__ row_ptr, const int* __restrict__ csr_row,
              const float* __restrict__ csr_w, const uint16_t* __restrict__ h_bf,
              uint16_t* __restrict__ agg,
              const int* __restrict__ row_ptr2, const int* __restrict__ tcsr,
              const float* __restrict__ out_e, const float* __restrict__ deg_inv,
              uint16_t* __restrict__ m_edge_bf)
{
    int n = blockIdx.x * 4 + (threadIdx.x >> 6);
    if (n >= N_NODES) return;
    int lane = threadIdx.x & 63;

    // agg[n] = sum w_norm * h_bf[row]
    int s = row_ptr[n], t = row_ptr[n + 1];
    float a0 = 0.f, a1 = 0.f;
    for (int j = s; j < t; ++j) {
        int r = csr_row[j];
        float w = csr_w[j];
        uint32_t v = *(const uint32_t*)(h_bf + (size_t)r * HDIM + lane * 2);
        a0 += w * bf2f(v & 0xffffu);
        a1 += w * bf2f(v >> 16);
    }
    *(uint32_t*)(agg + (size_t)n * HDIM + lane * 2) = f2bf(a0) | (f2bf(a1) << 16);

    // m_edge[n] = deg_inv[n] * sum over incident tie edges of e_work[e]
    int s2 = row_ptr2[n], t2 = row_ptr2[n + 1];
    float b0 = 0.f, b1 = 0.f;
    for (int j = s2; j < t2; ++j) {
        int e = tcsr[j];
        float2 v = *(const float2*)(out_e + (size_t)e * HDIM + lane * 2);
        b0 += v.x; b1 += v.y;
    }
    float di = deg_inv[n];
    *(uint32_t*)(m_edge_bf + (size_t)n * HDIM + lane * 2) =
        f2bf(b0 * di) | (f2bf(b1 * di) << 16);
}

// ---------------- fused node kernel (bf16 m_edge; GRU ping-pong B) ----------
__global__ __launch_bounds__(512)
void k_node_mega(const uint16_t* __restrict__ m_edge_bf,
                 const uint16_t* __restrict__ agg,
                 float* __restrict__ out_h, uint16_t* __restrict__ h_bf,
                 const float* __restrict__ cpl_cnt, const float* __restrict__ sumw,
                 const short* __restrict__ BTnn, const float* __restrict__ b_nn,
                 const short* __restrict__ BTg1, const float* __restrict__ b_g1,
                 const float* __restrict__ Wg2, const float* __restrict__ b_g2,
                 const short* __restrict__ BTcomb,
                 const short* __restrict__ BTihn, const short* __restrict__ BThhn,
                 const float* __restrict__ b_ih, const float* __restrict__ b_hh)
{
    const int m0 = blockIdx.x * 128;
    __shared__ __align__(16) char Tme[32 * 1024];   // m_edge tile; reused as B buf in GRU
    __shared__ __align__(16) char Tmn[32 * 1024];   // agg -> m_node -> M
    __shared__ __align__(16) char Th [32 * 1024];
    __shared__ __align__(16) char Bt [32 * 1024];
    __shared__ float g_red[4][128];
    __shared__ float g_fin[128];
    __shared__ float sw_s[128];

    const int tid = threadIdx.x, lane = tid & 63;
    const int wid = tid >> 6, wr = wid >> 2, wc = wid & 3;

    stage_bf128(m_edge_bf, nullptr, m0, N_NODES, Tme, tid);
    stage_bf128(agg,       nullptr, m0, N_NODES, Tmn, tid);
    stage_bf128(h_bf,      nullptr, m0, N_NODES, Th,  tid);
    stage_b128(BTnn, 128, 0, 0, Bt, tid);
    if (tid < 128) {
        int n = m0 + tid; if (n >= N_NODES) n = N_NODES - 1;
        sw_s[tid] = sumw[n];
    }
    __syncthreads();

    // ---- phase 0: m_node = agg @ W_nn + sumw*b_nn  -> bf16 into Tmn ----
    {
        f32x4 accM[4][2] = {};
        mfma128(Tmn, Bt, wr, wc, lane, accM);
        __syncthreads();
        #pragma unroll
        for (int ni = 0; ni < 2; ++ni) {
            int col = wc * 32 + ni * 16 + (lane & 15);
            float bv = b_nn[col];
            #pragma unroll
            for (int mi = 0; mi < 4; ++mi)
                #pragma unroll
                for (int j = 0; j < 4; ++j) {
                    int rl = wr * 64 + mi * 16 + ((lane >> 4) << 2) + j;
                    float v = accM[mi][ni][j] + sw_s[rl] * bv;
                    *(uint16_t*)(Tmn + rl * 256 + ((col * 2) ^ ((rl & 7) << 4))) =
                        (uint16_t)f2bf(v);
                }
        }
        __syncthreads();
    }

    // ---- gate GEMM: [me|mn|h](K=384) @ W_g1 ----
    f32x4 accG[4][2] = {};
    #pragma unroll 1
    for (int c = 0; c < 3; ++c) {
        const char* Ac = (c == 0) ? Tme : (c == 1) ? Tmn : Th;
        stage_b128(BTg1, 384, 0, c * 128, Bt, tid);
        __syncthreads();
        mfma128(Ac, Bt, wr, wc, lane, accG);
        __syncthreads();
    }
    {
        float bg[2], wg[2];
        #pragma unroll
        for (int ni = 0; ni < 2; ++ni) {
            int col = wc * 32 + ni * 16 + (lane & 15);
            bg[ni] = b_g1[col]; wg[ni] = Wg2[col];
        }
        #pragma unroll
        for (int mi = 0; mi < 4; ++mi)
            #pragma unroll
            for (int j = 0; j < 4; ++j) {
                float p = fmaxf(accG[mi][0][j] + bg[0], 0.f) * wg[0]
                        + fmaxf(accG[mi][1][j] + bg[1], 0.f) * wg[1];
                #pragma unroll
                for (int o = 8; o; o >>= 1) p += __shfl_xor(p, o);
                if ((lane & 15) == 0)
                    g_red[wc][wr * 64 + mi * 16 + ((lane >> 4) << 2) + j] = p;
            }
    }
    __syncthreads();
    if (tid < 128) {
        float t = g_red[0][tid] + g_red[1][tid] + g_red[2][tid] + g_red[3][tid]
                + b_g2[0];
        g_fin[tid] = 1.f / (1.f + __expf(-t));
    }
    __syncthreads();

    // M = me + g*mn (in place of Tmn); C0 staged alongside (independent bufs)
    stage_b128(BTcomb, 256, 0, 0, Bt, tid);
    {
        const int c = tid & 15;
        #pragma unroll
        for (int p = 0; p < 4; ++p) {
            int row = p * 32 + (tid >> 4);
            float g = g_fin[row];
            int sw = (row & 7) << 4;
            #pragma unroll
            for (int hh = 0; hh < 2; ++hh) {
                int off = (c * 8 + hh * 128) ^ sw;
                uint2 me2 = *(uint2*)(Tme + row * 256 + off);
                uint2 mn2 = *(uint2*)(Tmn + row * 256 + off);
                *(uint2*)(Tmn + row * 256 + off) =
                    make_uint2(comb2(me2.x, mn2.x, g), comb2(me2.y, mn2.y, g));
            }
        }
    }
    __syncthreads();    // covers M-combine + C0 stage; Tme now DEAD -> B buffer

    // ---- GRU phases: ping-pong B between Bt and Tme (6 syncs, loads hidden)
    f32x4 aR[4][2] = {}, aZ[4][2] = {}, aGI[4][2] = {}, aGH[4][2] = {};
    stage_b128(BTcomb, 256, 0, 128, Tme, tid);
    mfma128(Tmn, Bt, wr, wc, lane, aR);   __syncthreads();
    stage_b128(BTcomb, 256, 128, 0, Bt, tid);
    mfma128(Th, Tme, wr, wc, lane, aR);   __syncthreads();
    stage_b128(BTcomb, 256, 128, 128, Tme, tid);
    mfma128(Tmn, Bt, wr, wc, lane, aZ);   __syncthreads();
    stage_b128(BTihn, 128, 0, 0, Bt, tid);
    mfma128(Th, Tme, wr, wc, lane, aZ);   __syncthreads();
    stage_b128(BThhn, 128, 0, 0, Tme, tid);
    mfma128(Tmn, Bt, wr, wc, lane, aGI);  __syncthreads();
    mfma128(Th, Tme, wr, wc, lane, aGH);

    // ---- GRU epilogue (masked); maintains h_bf shadow ----
    #pragma unroll
    for (int ni = 0; ni < 2; ++ni) {
        int col = wc * 32 + ni * 16 + (lane & 15);
        float br  = b_ih[col] + b_hh[col];
        float bz  = b_ih[128 + col] + b_hh[128 + col];
        float bin = b_ih[256 + col], bhn = b_hh[256 + col];
        #pragma unroll
        for (int mi = 0; mi < 4; ++mi)
            #pragma unroll
            for (int j = 0; j < 4; ++j) {
                int node = m0 + wr * 64 + mi * 16 + ((lane >> 4) << 2) + j;
                if (node < N_NODES && cpl_cnt[node] > 0.f) {
                    float r = 1.f / (1.f + __expf(-(aR[mi][ni][j] + br)));
                    float z = 1.f / (1.f + __expf(-(aZ[mi][ni][j] + bz)));
                    float nn = tanhf(aGI[mi][ni][j] + bin + r * (aGH[mi][ni][j] + bhn));
                    size_t hb = (size_t)node * HDIM + col;
                    float hv = out_h[hb];
                    float hn = (1.f - z) * nn + z * hv;
                    out_h[hb] = hn;
                    h_bf[hb] = (uint16_t)f2bf(hn);
                }
            }
    }
}

// ---------------- k_init: block-partitioned prep ----------------
// [0,2048): e->out_e  [2048,2304): h->out_h+h_bf  [2304,2368): node zero
// [2368,2496): weights  2496: fmt detect
#define INIT_BLOCKS 2497

__global__ __launch_bounds__(256)
void k_init(const float* __restrict__ e, float* __restrict__ out_e,
            const float* __restrict__ h, float* __restrict__ out_h,
            uint16_t* __restrict__ h_bf,
            float* __restrict__ cpl_cnt, float* __restrict__ w_den,
            int* __restrict__ hist, int* __restrict__ counters,
            const uint8_t* __restrict__ tie_raw,
            const float* __restrict__ W_er1, const float* __restrict__ W_er2,
            const float* __restrict__ W_nn, const float* __restrict__ W_g1,
            const float* __restrict__ W_ih, const float* __restrict__ W_hh,
            short* __restrict__ BTer1, short* __restrict__ BTer2,
            short* __restrict__ BTnn, short* __restrict__ BTg1,
            short* __restrict__ BTcomb, short* __restrict__ BTihn,
            short* __restrict__ BThhn)
{
    const int b = blockIdx.x, t = threadIdx.x;
    if (b < 2048) {
        const float4* src = (const float4*)e;
        float4* dst = (float4*)out_e;
        for (int i = b * 256 + t; i < N_EDGES * HDIM / 4; i += 2048 * 256)
            dst[i] = src[i];
    } else if (b < 2304) {
        for (int i = (b - 2048) * 256 + t; i < N_NODES * HDIM / 4; i += 256 * 256) {
            float4 v = ((const float4*)h)[i];
            ((float4*)out_h)[i] = v;
            *(uint2*)(h_bf + (size_t)i * 4) =
                make_uint2(f2bf(v.x) | (f2bf(v.y) << 16),
                           f2bf(v.z) | (f2bf(v.w) << 16));
        }
    } else if (b < 2368) {
        for (int i = (b - 2304) * 256 + t; i < N_NODES; i += 64 * 256) {
            cpl_cnt[i] = 0.f; w_den[i] = 0.f; hist[i] = 0;
        }
    } else if (b < 2496) {
        for (int i = (b - 2368) * 256 + t; i < 384 * 256; i += 128 * 256) {
            {   int n = i / 384, k = i % 384;
                BTer1[i] = (short)f2bf(W_er1[(size_t)k * 256 + n]); }
            if (i < 128 * 256) {
                int n = i / 256, k = i % 256;
                BTer2[i] = (short)f2bf(W_er2[(size_t)k * 128 + n]); }
            if (i < 128 * 128) {
                int n = i / 128, k = i % 128;
                BTnn[i] = (short)f2bf(W_nn[(size_t)k * 128 + n]); }
            if (i < 128 * 384) {
                int n = i / 384, k = i % 384;
                BTg1[i] = (short)f2bf(W_g1[(size_t)k * 128 + n]); }
            if (i < 256 * 256) {
                int n = i >> 8, k = i & 255;
                float v = (k < 128) ? W_ih[n * 128 + k] : W_hh[n * 128 + (k - 128)];
                BTcomb[i] = (short)f2bf(v); }
            if (i < 128 * 128) {
                BTihn[i] = (short)f2bf(W_ih[256 * 128 + i]);
                BThhn[i] = (short)f2bf(W_hh[256 * 128 + i]); }
        }
    } else {
        if (t < 64) {
            int c = 0;
            for (int k = t; k < 4096; k += 64)
                if ((k & 3) && tie_raw[k]) c = 1;
            unsigned long long m = __ballot(c != 0);
            if (t == 0) {
                counters[0] = (m != 0ull) ? 1 : 0;
                counters[1] = 0; counters[2] = 0; counters[3] = 0;
            }
        }
    }
}

// ---------------- tie classification (wave-aggregated compaction) -----------
__global__ __launch_bounds__(256)
void k_tie(const void* __restrict__ tie_raw, const int* __restrict__ counters,
           const int* __restrict__ ei, float* __restrict__ cpl_cnt,
           int* __restrict__ tie_cnt, int* __restrict__ tie_list,
           int* __restrict__ tie_row, int* __restrict__ tie_col)
{
    int e = blockIdx.x * 256 + threadIdx.x;
    int fmt = counters[0];
    bool t = false; int r = 0, c = 0;
    if (e < N_EDGES)
        t = fmt ? (((const uint8_t*)tie_raw)[e] != 0)
                : (((const int*)tie_raw)[e] != 0);
    if (t) {
        r = ei[e]; c = ei[N_EDGES + e];
        atomicAdd(&cpl_cnt[r], 1.f);
        atomicAdd(&cpl_cnt[c], 1.f);
    }
    unsigned long long m = __ballot(t);
    if (m == 0ull) return;
    int lane = threadIdx.x & 63;
    int first = __ffsll((unsigned long long)m) - 1;
    int base = 0;
    if (lane == first) base = atomicAdd(tie_cnt, __popcll(m));
    base = __shfl(base, first);
    if (t) {
        int idx = base + __popcll(m & ((1ull << lane) - 1ull));
        if (idx < TIE_CAP) { tie_list[idx] = e; tie_row[idx] = r; tie_col[idx] = c; }
    }
}

__global__ __launch_bounds__(256)
void k_w(const void* __restrict__ tie_raw, const int* __restrict__ counters,
         const int* __restrict__ ei, const float* __restrict__ attr,
         const float* __restrict__ cpl_cnt, float* __restrict__ w_den,
         float* __restrict__ w_arr, int* __restrict__ hist)
{
    int e = blockIdx.x * 256 + threadIdx.x;
    if (e >= N_EDGES) return;
    int fmt = counters[0];
    bool t = fmt ? (((const uint8_t*)tie_raw)[e] != 0)
                 : (((const int*)tie_raw)[e] != 0);
    float w = 0.f;
    if (!t) {
        int c = ei[N_EDGES + e];
        if (cpl_cnt[c] > 0.f) {
            float X = fabsf(attr[(size_t)e * 10 + 1]);
            w = 1.f / sqrtf(X * X + 1e-6f);
            atomicAdd(&w_den[c], w);
            atomicAdd(&hist[c], 1);
        }
    }
    w_arr[e] = w;
}

// ---------------- dual CSR build (internal-edge CSR + tie-incidence CSR) ----
__global__ __launch_bounds__(SCAN_B)
void k_scan1(const int* __restrict__ hist, const float* __restrict__ cpl_cnt,
             int* __restrict__ excl, int* __restrict__ bsum,
             int* __restrict__ excl2, int* __restrict__ bsum2)
{
    __shared__ int s[SCAN_B];
    int t = threadIdx.x;
    int i = blockIdx.x * SCAN_B + t;
    int v = (i < N_NODES) ? hist[i] : 0;
    s[t] = v;
    __syncthreads();
    for (int o = 1; o < SCAN_B; o <<= 1) {
        int u = (t >= o) ? s[t - o] : 0;
        __syncthreads();
        s[t] += u;
        __syncthreads();
    }
    if (i < N_NODES) excl[i] = s[t] - v;
    if (t == SCAN_B - 1) bsum[blockIdx.x] = s[t];
    __syncthreads();
    int v2 = (i < N_NODES) ? (int)cpl_cnt[i] : 0;
    s[t] = v2;
    __syncthreads();
    for (int o = 1; o < SCAN_B; o <<= 1) {
        int u = (t >= o) ? s[t - o] : 0;
        __syncthreads();
        s[t] += u;
        __syncthreads();
    }
    if (i < N_NODES) excl2[i] = s[t] - v2;
    if (t == SCAN_B - 1) bsum2[blockIdx.x] = s[t];
}

__global__ void k_scan2(int* __restrict__ bsum, int* __restrict__ bsum2,
                        int* __restrict__ counters)
{
    const int NB = (N_NODES + SCAN_B - 1) / SCAN_B;
    if (threadIdx.x == 0) {
        int run = 0;
        for (int b = 0; b < NB; ++b) { int x = bsum[b]; bsum[b] = run; run += x; }
        counters[2] = run;
        int run2 = 0;
        for (int b = 0; b < NB; ++b) { int x = bsum2[b]; bsum2[b] = run2; run2 += x; }
        counters[3] = run2;
    }
}

__global__ __launch_bounds__(256)
void k_scan3(const int* __restrict__ excl, const int* __restrict__ bsum,
             const int* __restrict__ excl2, const int* __restrict__ bsum2,
             int* __restrict__ row_ptr, int* __restrict__ cursor,
             int* __restrict__ row_ptr2, int* __restrict__ cursor2,
             const int* __restrict__ counters,
             const float* __restrict__ cpl_cnt, const float* __restrict__ w_den,
             float* __restrict__ deg_inv, float* __restrict__ sumw)
{
    int i = blockIdx.x * 256 + threadIdx.x;
    if (i < N_NODES) {
        int v = excl[i] + bsum[i >> 8];
        row_ptr[i] = v;  cursor[i] = v;
        int v2 = excl2[i] + bsum2[i >> 8];
        row_ptr2[i] = v2; cursor2[i] = v2;
        deg_inv[i] = 1.f / fmaxf(cpl_cnt[i], 1.f);
        float wd = w_den[i];
        sumw[i] = wd / (wd + 1e-6f);
    }
    if (i == N_NODES) {
        row_ptr[N_NODES] = counters[2];
        row_ptr2[N_NODES] = counters[3];
    }
}

// blocks [0,EB_CONST): internal-edge CSR fill; [EB_CONST, +TB): tie-CSR fill
__global__ __launch_bounds__(256)
void k_fill(const int* __restrict__ ei, const float* __restrict__ w_arr,
            const float* __restrict__ w_den, int* __restrict__ cursor,
            int* __restrict__ csr_row, float* __restrict__ csr_w,
            const int* __restrict__ counters, const int* __restrict__ tie_list,
            const int* __restrict__ tie_row, const int* __restrict__ tie_col,
            int* __restrict__ cursor2, int* __restrict__ tcsr)
{
    int b = blockIdx.x;
    if (b < EB_CONST) {
        int e = b * 256 + threadIdx.x;
        if (e >= N_EDGES) return;
        float w = w_arr[e];
        if (w == 0.f) return;
        int c = ei[N_EDGES + e];
        int pos = atomicAdd(&cursor[c], 1);
        csr_row[pos] = ei[e];
        csr_w[pos] = w / (w_den[c] + 1e-6f);
    } else {
        int i = (b - EB_CONST) * 256 + threadIdx.x;
        int cnt = counters[1]; if (cnt > TIE_CAP) cnt = TIE_CAP;
        if (i < cnt) {
            int e = tie_list[i];
            int p1 = atomicAdd(&cursor2[tie_row[i]], 1); tcsr[p1] = e;
            int p2 = atomicAdd(&cursor2[tie_col[i]], 1); tcsr[p2] = e;
        }
    }
}

// ---------------- launch ----------------
extern "C" void kernel_launch(void* const* d_in, const int* in_sizes, int n_in,
                              void* d_out, int out_size, void* d_ws, size_t ws_size,
                              hipStream_t stream)
{
    const float* h     = (const float*)d_in[0];
    const float* e     = (const float*)d_in[1];
    const float* attr  = (const float*)d_in[2];
    const float* W_er1 = (const float*)d_in[3];
    const float* b_er1 = (const float*)d_in[4];
    const float* W_er2 = (const float*)d_in[5];
    const float* b_er2 = (const float*)d_in[6];
    const float* W_ih  = (const float*)d_in[7];
    const float* W_hh  = (const float*)d_in[8];
    const float* b_ih  = (const float*)d_in[9];
    const float* b_hh  = (const float*)d_in[10];
    const float* W_nn  = (const float*)d_in[11];
    const float* b_nn  = (const float*)d_in[12];
    const float* W_g1  = (const float*)d_in[13];
    const float* b_g1  = (const float*)d_in[14];
    const float* W_g2  = (const float*)d_in[15];
    const float* b_g2  = (const float*)d_in[16];
    const int*   ei    = (const int*)d_in[17];
    const void*  tie_raw = d_in[18];

    float* out_h = (float*)d_out;
    float* out_e = out_h + (size_t)N_NODES * HDIM;

    char* ws = (char*)d_ws;
    size_t off = 0;
    auto alloc = [&](size_t bytes) -> void* {
        void* p = ws + off;
        off = (off + bytes + 255) & ~(size_t)255;
        return p;
    };
    float* cpl_cnt = (float*)alloc((size_t)N_NODES * 4);
    float* w_den   = (float*)alloc((size_t)N_NODES * 4);
    int*   hist    = (int*)  alloc((size_t)N_NODES * 4);
    int*   counters= (int*)  alloc(256);  // [0]=fmt [1]=tie_cnt [2]=csr [3]=tcsr
    float* deg_inv = (float*)alloc((size_t)N_NODES * 4);
    float* sumw    = (float*)alloc((size_t)N_NODES * 4);
    float* w_arr   = (float*)alloc((size_t)N_EDGES * 4);
    int* tie_list  = (int*)alloc((size_t)TIE_CAP * 4);
    int* tie_row   = (int*)alloc((size_t)TIE_CAP * 4);
    int* tie_col   = (int*)alloc((size_t)TIE_CAP * 4);
    short* BTer1   = (short*)alloc((size_t)256 * 384 * 2);
    short* BTer2   = (short*)alloc((size_t)128 * 256 * 2);
    short* BTnn    = (short*)alloc((size_t)128 * 128 * 2);
    short* BTg1    = (short*)alloc((size_t)128 * 384 * 2);
    short* BTcomb  = (short*)alloc((size_t)256 * 256 * 2);
    short* BTihn   = (short*)alloc((size_t)128 * 128 * 2);
    short* BThhn   = (short*)alloc((size_t)128 * 128 * 2);
    uint16_t* h_bf = (uint16_t*)alloc((size_t)N_NODES * HDIM * 2);
    uint16_t* agg  = (uint16_t*)alloc((size_t)N_NODES * HDIM * 2);
    uint16_t* m_edge_bf = (uint16_t*)alloc((size_t)N_NODES * HDIM * 2);
    int* excl      = (int*)alloc((size_t)N_NODES * 4);
    int* excl2     = (int*)alloc((size_t)N_NODES * 4);
    int* bsum      = (int*)alloc(256 * 4);
    int* bsum2     = (int*)alloc(256 * 4);
    int* row_ptr   = (int*)alloc((size_t)(N_NODES + 1) * 4);
    int* row_ptr2  = (int*)alloc((size_t)(N_NODES + 1) * 4);
    int* cursor    = (int*)alloc((size_t)N_NODES * 4);
    int* cursor2   = (int*)alloc((size_t)N_NODES * 4);
    int* csr_row   = (int*)alloc((size_t)N_EDGES * 4);
    float* csr_w   = (float*)alloc((size_t)N_EDGES * 4);
    int* tcsr      = (int*)alloc((size_t)2 * TIE_CAP * 4);
    if (off > ws_size) return;

    int* tie_cnt = counters + 1;

    const int GM_T = (TIE_CAP + 127) / 128;          // 344
    const int GM_N = (N_NODES + 127) / 128;          // 391
    const int NB   = (N_NODES + SCAN_B - 1) / SCAN_B;

    k_init<<<INIT_BLOCKS, 256, 0, stream>>>(
        e, out_e, h, out_h, h_bf, cpl_cnt, w_den, hist, counters,
        (const uint8_t*)tie_raw,
        W_er1, W_er2, W_nn, W_g1, W_ih, W_hh,
        BTer1, BTer2, BTnn, BTg1, BTcomb, BTihn, BThhn);
    k_tie<<<EB_CONST, 256, 0, stream>>>(tie_raw, counters, ei, cpl_cnt,
                                        tie_cnt, tie_list, tie_row, tie_col);
    k_w<<<EB_CONST, 256, 0, stream>>>(tie_raw, counters, ei, attr, cpl_cnt,
                                      w_den, w_arr, hist);
    k_scan1<<<NB, SCAN_B, 0, stream>>>(hist, cpl_cnt, excl, bsum, excl2, bsum2);
    k_scan2<<<1, 64, 0, stream>>>(bsum, bsum2, counters);
    k_scan3<<<(N_NODES + 256) / 256, 256, 0, stream>>>(
        excl, bsum, excl2, bsum2, row_ptr, cursor, row_ptr2, cursor2,
        counters, cpl_cnt, w_den, deg_inv, sumw);
    k_fill<<<EB_CONST + TB_CONST, 256, 0, stream>>>(
        ei, w_arr, w_den, cursor, csr_row, csr_w,
        counters, tie_list, tie_row, tie_col, cursor2, tcsr);

    for (int it = 0; it < NITER; ++it) {
        k_tie_fused<<<GM_T, 512, 0, stream>>>(
            out_e, h_bf, tie_cnt, tie_list, tie_row, tie_col,
            BTer1, BTer2, b_er1, b_er2);
        k_gather<<<(N_NODES + 3) / 4, 256, 0, stream>>>(
            row_ptr, csr_row, csr_w, h_bf, agg,
            row_ptr2, tcsr, out_e, deg_inv, m_edge_bf);
        k_node_mega<<<GM_N, 512, 0, stream>>>(
            m_edge_bf, agg, out_h, h_bf, cpl_cnt, sumw,
            BTnn, b_nn, BTg1, b_g1, W_g2, b_g2,
            BTcomb, BTihn, BThhn, b_ih, b_hh);
    }
}